// Round 7
// baseline (1114.787 us; speedup 1.0000x reference)
//
#include <hip/hip_runtime.h>
#include <stdint.h>

// ---------------------------------------------------------------------------
// GIN (4 layers, CSR gather aggregation) + MLP classifier, bf16 MFMA GEMMs.
// R6 change: channel-sliced XCD-pinned aggregation.
//   R2/R5 agg both pinned at 3.4 TB/s with FETCH 188MB: the 25.6MB h-table
//   exceeds per-XCD 4MB L2 -> L2-miss path ceiling. Now h/zin live in sliced
//   layout [8][N][SW] (SW=16ch for C=128, 8ch for C=64); agg blocks are
//   (4 nodes x 1 slice) with blockIdx.x%8=slice -> slice pinned to one XCD,
//   3.2MB working set fits its L2. colb re-read 8x (sequential, cheap).
//   GEMM staging/epilogue + xconv get sliced addressing; classifier flat.
// ---------------------------------------------------------------------------

#define NN  100000
#define EE  1600000
#define CIN 64
#define CC  128
#define NBK 782              // ceil(NN / 128) buckets, bucket = dst >> 7
#define CHUNK 8192           // edges per multi-split block
#define NCH 196              // ceil(EE / CHUNK)

typedef __attribute__((ext_vector_type(8))) __bf16 bf16x8;
typedef __attribute__((ext_vector_type(4))) float  f32x4;

__device__ __forceinline__ float bf2f(uint32_t u) { return __uint_as_float(u << 16); }
__device__ __forceinline__ float bf2f_hi(uint32_t u) { return __uint_as_float(u & 0xffff0000u); }
__device__ __forceinline__ ushort f2bf(float f) {          // RNE f32 -> bf16
  uint32_t u = __float_as_uint(f);
  u += 0x7fffu + ((u >> 16) & 1u);
  return (ushort)(u >> 16);
}

template<int ACT> __device__ __forceinline__ float actf(float z) {
  if constexpr (ACT == 1) return z >= 0.f ? z : 0.01f * z;       // lrelu
  else if constexpr (ACT == 2) return z >= 0.f ? z : 1e-4f * z;  // lrelu(lrelu)
  else return z;
}

// ---------------- multi-split CSR build ----------------
__global__ __launch_bounds__(256) void ms_hist_kernel(const int* __restrict__ ei,
                                                      int* __restrict__ hist,
                                                      int* __restrict__ bh, int e) {
  __shared__ int h[NBK];
  for (int i = threadIdx.x; i < NBK; i += 256) h[i] = 0;
  __syncthreads();
  const int base = blockIdx.x * CHUNK;
  const int end = min(base + CHUNK, e);
  for (int i = base + threadIdx.x; i < end; i += 256)
    atomicAdd(&h[ei[e + i] >> 7], 1);
  __syncthreads();
  for (int i = threadIdx.x; i < NBK; i += 256) {
    hist[blockIdx.x * NBK + i] = h[i];
    if (h[i]) atomicAdd(&bh[i], h[i]);
  }
}

__global__ __launch_bounds__(256) void bkt_scan_kernel(const int* __restrict__ bh,
                                                       int* __restrict__ boff, int e) {
  __shared__ int sd[256];
  int t = threadIdx.x;
  int base = t * 4;
  int v0 = base + 0 < NBK ? bh[base + 0] : 0;
  int v1 = base + 1 < NBK ? bh[base + 1] : 0;
  int v2 = base + 2 < NBK ? bh[base + 2] : 0;
  int v3 = base + 3 < NBK ? bh[base + 3] : 0;
  int ts = v0 + v1 + v2 + v3;
  sd[t] = ts; __syncthreads();
  for (int off = 1; off < 256; off <<= 1) {
    int u = (t >= off) ? sd[t - off] : 0;
    __syncthreads();
    sd[t] += u;
    __syncthreads();
  }
  int excl = sd[t] - ts;
  if (base + 0 < NBK) boff[base + 0] = excl;
  if (base + 1 < NBK) boff[base + 1] = excl + v0;
  if (base + 2 < NBK) boff[base + 2] = excl + v0 + v1;
  if (base + 3 < NBK) boff[base + 3] = excl + v0 + v1 + v2;
  if (t == 255) boff[NBK] = e;
}

__global__ void ms_offs_kernel(int* __restrict__ hist, const int* __restrict__ boff) {
  int b = blockIdx.x * 256 + threadIdx.x;
  if (b >= NBK) return;
  int run = boff[b];
  for (int k = 0; k < NCH; ++k) {
    int t = hist[k * NBK + b];     // coalesced across b
    hist[k * NBK + b] = run;
    run += t;
  }
}

__global__ __launch_bounds__(256) void ms_scatter_kernel(const int* __restrict__ ei,
                                                         const int* __restrict__ hist,
                                                         uint* __restrict__ ebkt, int e) {
  __shared__ int cur[NBK];
  for (int i = threadIdx.x; i < NBK; i += 256) cur[i] = hist[blockIdx.x * NBK + i];
  __syncthreads();
  const int base = blockIdx.x * CHUNK;
  const int end = min(base + CHUNK, e);
  for (int i = base + threadIdx.x; i < end; i += 256) {
    int s = ei[i], d = ei[e + i];
    int p = atomicAdd(&cur[d >> 7], 1);
    ebkt[p] = ((uint)(d & 127) << 17) | (uint)s;
  }
}

__global__ __launch_bounds__(256) void bkt_deg_kernel(const uint* __restrict__ ebkt,
                                                      const int* __restrict__ boff,
                                                      int* __restrict__ deg, int n) {
  __shared__ int dl[128];
  int b = blockIdx.x;
  for (int i = threadIdx.x; i < 128; i += 256) dl[i] = 0;
  __syncthreads();
  int j1 = boff[b + 1];
  for (int j = boff[b] + threadIdx.x; j < j1; j += 256)
    atomicAdd(&dl[ebkt[j] >> 17], 1);
  __syncthreads();
  for (int i = threadIdx.x; i < 128; i += 256) {
    int node = (b << 7) + i;
    if (node < n) deg[node] = dl[i];
  }
}

__global__ __launch_bounds__(256) void bkt_fill_kernel(const uint* __restrict__ ebkt,
                                                       const int* __restrict__ boff,
                                                       const int* __restrict__ rowp,
                                                       int* __restrict__ colb, int n) {
  __shared__ int cur[128];
  int b = blockIdx.x;
  for (int i = threadIdx.x; i < 128; i += 256) {
    int node = (b << 7) + i;
    cur[i] = (node < n) ? rowp[node] : 0;
  }
  __syncthreads();
  int j1 = boff[b + 1];
  for (int j = boff[b] + threadIdx.x; j < j1; j += 256) {
    uint v = ebkt[j];
    int p = atomicAdd(&cur[v >> 17], 1);
    colb[p] = (int)(v & 0x1FFFFu);
  }
}

// ---------------- node-degree scan (rowp) ----------------
__global__ void scan1_kernel(const int* __restrict__ deg, int* __restrict__ outp,
                             int* __restrict__ partial, int n) {
  __shared__ int sd[256];
  int t = threadIdx.x;
  int base = blockIdx.x * 1024 + t * 4;
  int v0 = base + 0 < n ? deg[base + 0] : 0;
  int v1 = base + 1 < n ? deg[base + 1] : 0;
  int v2 = base + 2 < n ? deg[base + 2] : 0;
  int v3 = base + 3 < n ? deg[base + 3] : 0;
  int ts = v0 + v1 + v2 + v3;
  sd[t] = ts; __syncthreads();
  for (int off = 1; off < 256; off <<= 1) {
    int u = (t >= off) ? sd[t - off] : 0;
    __syncthreads();
    sd[t] += u;
    __syncthreads();
  }
  int excl = sd[t] - ts;
  if (base + 0 < n) outp[base + 0] = excl;
  if (base + 1 < n) outp[base + 1] = excl + v0;
  if (base + 2 < n) outp[base + 2] = excl + v0 + v1;
  if (base + 3 < n) outp[base + 3] = excl + v0 + v1 + v2;
  if (t == 255) partial[blockIdx.x] = sd[255];
}

__global__ void scan2_kernel(int* __restrict__ partial, int nb) {
  __shared__ int sd[256];
  int t = threadIdx.x;
  int v = t < nb ? partial[t] : 0;
  sd[t] = v; __syncthreads();
  for (int off = 1; off < 256; off <<= 1) {
    int u = (t >= off) ? sd[t - off] : 0;
    __syncthreads();
    sd[t] += u;
    __syncthreads();
  }
  if (t < nb) partial[t] = sd[t] - v;  // exclusive block offsets
}

__global__ void scan3_kernel(int* __restrict__ rowp, const int* __restrict__ partial,
                             int n, int e) {
  int i = blockIdx.x * 256 + threadIdx.x;
  if (i == 0) rowp[n] = e;
  if (i < n) rowp[i] += partial[i >> 10];
}

// ---------------- prep ----------------
__global__ void bnprep_kernel(const float* b1, const float* g1, const float* be1,
                              const float* m1, const float* v1,
                              const float* bL, const float* gL, const float* beL,
                              const float* mL, const float* vL,
                              float* __restrict__ sc, float* __restrict__ tc) {
  int i = blockIdx.x * 256 + threadIdx.x;
  if (i >= 4 * 128) return;
  int layer = i >> 7, c = i & 127;
  float b, g, be, m, v;
  if (layer == 0) { b = b1[c]; g = g1[c]; be = be1[c]; m = m1[c]; v = v1[c]; }
  else { int o = (layer - 1) * 128 + c; b = bL[o]; g = gL[o]; be = beL[o]; m = mL[o]; v = vL[o]; }
  float s = g * rsqrtf(v + 1e-5f);
  sc[i] = s;
  tc[i] = (b - m) * s + be;
}

// transpose fp32 weights -> bf16 Wt (M x K row-major)
__global__ void wtprep_kernel(const float* __restrict__ W1, const float* __restrict__ WL,
                              const float* __restrict__ Wc1, const float* __restrict__ Wcl,
                              ushort* __restrict__ wt1, ushort* __restrict__ wtL,
                              ushort* __restrict__ wtc1, ushort* __restrict__ wtcl) {
  int i = blockIdx.x * 256 + threadIdx.x;
  if (i < 8192) {                                      // W1: 64x128 -> 128x64
    int m = i >> 6, k = i & 63;
    wt1[i] = f2bf(W1[k * 128 + m]);
  } else if (i < 8192 + 49152) {                       // WL: 3 x 128x128
    int j = i - 8192;
    int l = j >> 14, r = j & 16383, m = r >> 7, k = r & 127;
    wtL[j] = f2bf(WL[l * 16384 + k * 128 + m]);
  } else if (i < 8192 + 49152 + 32768) {               // Wc1: 128x256 -> 256x128
    int j = i - (8192 + 49152);
    int m = j >> 7, k = j & 127;
    wtc1[j] = f2bf(Wc1[k * 256 + m]);
  } else if (i < 8192 + 49152 + 32768 + 131072) {      // Wcl: 2 x 256x256
    int j = i - (8192 + 49152 + 32768);
    int l = j >> 16, r = j & 65535, m = r >> 8, k = r & 255;
    wtcl[j] = f2bf(Wcl[l * 65536 + k * 256 + m]);
  }
}

// x fp32 [N][64] -> bf16 sliced8 [8][N][8]
__global__ void xconv_kernel(const float* __restrict__ x, ushort* __restrict__ xb, int n) {
  int i = blockIdx.x * 256 + threadIdx.x;
  if (i >= n * 16) return;
  int node = i >> 4, c4 = (i & 15) * 4;
  float4 v = *(const float4*)(x + (size_t)node * 64 + c4);
  ushort4 o;
  o.x = f2bf(v.x); o.y = f2bf(v.y); o.z = f2bf(v.z); o.w = f2bf(v.w);
  int sl = c4 >> 3, off = c4 & 7;
  *(ushort4*)(xb + (size_t)sl * ((size_t)NN * 8) + (size_t)node * 8 + off) = o;
}

// ---------------- aggregation v3: sliced, XCD-pinned ----------------
// block = (4 nodes) x (1 slice); blockIdx.x%8 = slice -> one XCD's L2 holds
// its 3.2MB channel slice. Per edge: LPE lanes x dword (2ch).
template<int C>
__global__ __launch_bounds__(256) void agg_kernel(
    const ushort* __restrict__ hb,   // sliced [8][N][SW]
    const int* __restrict__ rowp,
    const int* __restrict__ colb, const float* __restrict__ ep,
    ushort* __restrict__ zout, int n)  // sliced [8][N][SW]
{
  constexpr int SW  = C / 8;           // slice width in channels (16 / 8)
  constexpr int LPE = SW / 2;          // lanes per edge (8 / 4)
  constexpr int EPR = 64 / LPE;        // edges per round (8 / 16)
  const int slice = blockIdx.x & 7;
  const int tile  = blockIdx.x >> 3;
  const int lane = threadIdx.x & 63;
  const int node = tile * 4 + (threadIdx.x >> 6);
  if (node >= n) return;
  const float e1 = 1.0f + ep[0];
  const int lo = lane & (LPE - 1);
  const int g  = lane / LPE;
  const ushort* hs = hb + (size_t)slice * ((size_t)n * SW);
  ushort* zs = zout + (size_t)slice * ((size_t)n * SW);

  int j0 = rowp[node], jend = rowp[node + 1];
  float a0 = 0.f, a1 = 0.f;
  for (; j0 < jend; j0 += 64) {
    int cnt = jend - j0; if (cnt > 64) cnt = 64;
    int myn = (lane < cnt) ? colb[j0 + lane] : 0;
    int rounds = (cnt + EPR - 1) / EPR;
    #pragma unroll 4
    for (int r = 0; r < rounds; ++r) {
      int e = r * EPR + g;
      int u = __shfl(myn, e);          // all lanes active for the shuffle
      if (e < cnt) {
        uint v = *(const uint*)(hs + (size_t)u * SW + lo * 2);
        a0 += bf2f(v); a1 += bf2f_hi(v);
      }
    }
  }
  #pragma unroll
  for (int s = LPE; s < 64; s <<= 1) {
    a0 += __shfl_xor(a0, s);
    a1 += __shfl_xor(a1, s);
  }
  if (g == 0) {
    uint d = *(const uint*)(hs + (size_t)node * SW + lo * 2);
    uint o = (uint)f2bf(e1 * bf2f(d) + a0) | ((uint)f2bf(e1 * bf2f_hi(d) + a1) << 16);
    *(uint*)(zs + (size_t)node * SW + lo * 2) = o;
  }
}

// ---------------- GEMM v3: block = 128 nodes x 128 ch, waves split M --------
// XS/OS = slice width of X / output layout (0 = flat [N][K] / [N][M]).
template<int K, int M, int XS, int OS, int ACT, bool BN>
__global__ __launch_bounds__(256) void gemm_kernel(
    const ushort* __restrict__ xin,
    const ushort* __restrict__ wt,    // M x K  bf16 (row-major)
    const float*  __restrict__ sc,
    const float*  __restrict__ tc,
    ushort* __restrict__ hout,
    int n)
{
  constexpr int KS = 64;
  __shared__ ushort ldsW[128 * KS];   // 16 KiB, XOR-swizzled rows
  __shared__ ushort ldsX[128 * KS];   // 16 KiB, XOR-swizzled rows
  const int tid = threadIdx.x;
  const int wave = tid >> 6, lane = tid & 63;
  const int lr = lane & 15, lg = lane >> 4;
  const int n0 = blockIdx.x * 128;
  const int mB = blockIdx.y * 128;

  f32x4 acc[8][2];
  #pragma unroll
  for (int r = 0; r < 8; ++r) {
    acc[r][0] = (f32x4){0.f, 0.f, 0.f, 0.f};
    acc[r][1] = (f32x4){0.f, 0.f, 0.f, 0.f};
  }

  #pragma unroll
  for (int s = 0; s < K / KS; ++s) {
    if (s) __syncthreads();
    // stage W chunk: rows mB..mB+127, k slab s (128x64 bf16)
    #pragma unroll
    for (int c0 = 0; c0 < 1024; c0 += 256) {
      int c = c0 + tid;
      int m = c >> 3, kc = c & 7;
      uint4 v = *(const uint4*)(wt + (size_t)(mB + m) * K + s * KS + kc * 8);
      *(uint4*)((char*)ldsW + ((m * 128 + kc * 16) ^ ((m & 7) << 4))) = v;
    }
    // stage X tile: nodes n0..n0+127, k slab s
    #pragma unroll
    for (int c0 = 0; c0 < 1024; c0 += 256) {
      int c = c0 + tid;
      int r = c >> 3, kc = c & 7;
      int nd = n0 + r; if (nd >= n) nd = n - 1;
      const ushort* xp;
      if constexpr (XS == 0) {
        xp = xin + (size_t)nd * K + s * KS + kc * 8;
      } else {
        int ch = s * KS + kc * 8;
        int sl = ch / XS, off = ch % XS;
        xp = xin + (size_t)sl * ((size_t)NN * XS) + (size_t)nd * XS + off;
      }
      uint4 v = *(const uint4*)xp;
      *(uint4*)((char*)ldsX + ((r * 128 + kc * 16) ^ ((r & 7) << 4))) = v;
    }
    __syncthreads();
    #pragma unroll
    for (int k0 = 0; k0 < KS; k0 += 32) {
      const int kb = (k0 + lg * 8) * 2;  // byte offset of this lane's 16B in a row
      bf16x8 wf0, wf1;
      {
        int m = wave * 32 + lr;
        wf0 = __builtin_bit_cast(bf16x8,
              *(const uint4*)((const char*)ldsW + ((m * 128 + kb) ^ ((m & 7) << 4))));
        m += 16;
        wf1 = __builtin_bit_cast(bf16x8,
              *(const uint4*)((const char*)ldsW + ((m * 128 + kb) ^ ((m & 7) << 4))));
      }
      #pragma unroll
      for (int r = 0; r < 8; ++r) {
        int xr = r * 16 + lr;
        bf16x8 xf = __builtin_bit_cast(bf16x8,
              *(const uint4*)((const char*)ldsX + ((xr * 128 + kb) ^ ((xr & 7) << 4))));
        acc[r][0] = __builtin_amdgcn_mfma_f32_16x16x32_bf16(wf0, xf, acc[r][0], 0, 0, 0);
        acc[r][1] = __builtin_amdgcn_mfma_f32_16x16x32_bf16(wf1, xf, acc[r][1], 0, 0, 0);
      }
    }
  }

  // epilogue: D col = node (lane&15), D rows = 4*lg + reg (consecutive channels)
  #pragma unroll
  for (int ct = 0; ct < 2; ++ct) {
    const int c0 = mB + wave * 32 + ct * 16 + lg * 4;
    float4 sv;
    if constexpr (BN) sv = *(const float4*)(sc + c0);
    else sv = make_float4(1.f, 1.f, 1.f, 1.f);
    const float4 tv = *(const float4*)(tc + c0);
    #pragma unroll
    for (int r = 0; r < 8; ++r) {
      const int node = n0 + r * 16 + lr;
      if (node < n) {
        const f32x4 a = acc[r][ct];
        ushort4 o;
        o.x = f2bf(actf<ACT>(a[0] * sv.x + tv.x));
        o.y = f2bf(actf<ACT>(a[1] * sv.y + tv.y));
        o.z = f2bf(actf<ACT>(a[2] * sv.z + tv.z));
        o.w = f2bf(actf<ACT>(a[3] * sv.w + tv.w));
        ushort* hp;
        if constexpr (OS == 0) {
          hp = hout + (size_t)node * M + c0;
        } else {
          int sl = c0 / OS, off = c0 % OS;
          hp = hout + (size_t)sl * ((size_t)NN * OS) + (size_t)node * OS + off;
        }
        *(ushort4*)hp = o;
      }
    }
  }
}

// ---------------- final: sigmoid(s . Wf + bf) ----------------
__global__ __launch_bounds__(256) void final_kernel(
    const ushort* __restrict__ s, const float* __restrict__ wf,
    const float* __restrict__ bfp, float* __restrict__ out, int n)
{
  const int lane = threadIdx.x & 63;
  const int node = blockIdx.x * 4 + (threadIdx.x >> 6);
  if (node >= n) return;
  const uint2 d = *(const uint2*)(s + (size_t)node * 256 + lane * 4);
  const float4 w = *(const float4*)(wf + lane * 4);
  float acc = bf2f(d.x & 0xffff) * w.x + bf2f(d.x >> 16) * w.y
            + bf2f(d.y & 0xffff) * w.z + bf2f(d.y >> 16) * w.w;
  for (int off = 32; off; off >>= 1) acc += __shfl_down(acc, off);
  if (lane == 0) out[node] = 1.f / (1.f + expf(-(acc + bfp[0])));
}

// ---------------- launch ----------------
extern "C" void kernel_launch(void* const* d_in, const int* in_sizes, int n_in,
                              void* d_out, int out_size, void* d_ws, size_t ws_size,
                              hipStream_t stream)
{
  const float* x    = (const float*)d_in[0];
  const int*   ei   = (const int*)d_in[1];
  const float* eps1 = (const float*)d_in[3];
  const float* W1   = (const float*)d_in[4];
  const float* b1   = (const float*)d_in[5];
  const float* g1   = (const float*)d_in[6];
  const float* be1  = (const float*)d_in[7];
  const float* m1   = (const float*)d_in[8];
  const float* v1   = (const float*)d_in[9];
  const float* epsL = (const float*)d_in[10];
  const float* WL   = (const float*)d_in[11];
  const float* bL   = (const float*)d_in[12];
  const float* gL   = (const float*)d_in[13];
  const float* beL  = (const float*)d_in[14];
  const float* mL   = (const float*)d_in[15];
  const float* vL   = (const float*)d_in[16];
  const float* Wc1  = (const float*)d_in[17];
  const float* bc1  = (const float*)d_in[18];
  const float* Wcl  = (const float*)d_in[19];
  const float* bcl  = (const float*)d_in[20];
  const float* Wf   = (const float*)d_in[21];
  const float* bfp  = (const float*)d_in[22];
  float* out = (float*)d_out;

  char* w = (char*)d_ws;
  size_t off = 0;
  auto alloc = [&](size_t bytes) {
    char* p = w + off;
    off += (bytes + 255) & ~(size_t)255;
    return p;
  };
  ushort* bufA   = (ushort*)alloc((size_t)NN * 256 * 2);   // 51.2 MB
  ushort* bufB   = (ushort*)alloc((size_t)NN * 256 * 2);   // 51.2 MB
  int*    rowp   = (int*)alloc((NN + 1) * 4);
  int*    deg    = (int*)alloc(NN * 4);
  int*    colb   = (int*)alloc((size_t)EE * 4);
  uint*   ebkt   = (uint*)alloc((size_t)EE * 4);
  int*    hist   = (int*)alloc((size_t)NCH * NBK * 4);     // 613 KB
  int*    bh     = (int*)alloc(NBK * 4);
  int*    boff   = (int*)alloc((NBK + 1) * 4);
  int*    partial= (int*)alloc(1024);
  ushort* wt1    = (ushort*)alloc(8192 * 2);
  ushort* wtL    = (ushort*)alloc(49152 * 2);
  ushort* wtc1   = (ushort*)alloc(32768 * 2);
  ushort* wtcl   = (ushort*)alloc(131072 * 2);
  float*  sc     = (float*)alloc(512 * 4);
  float*  tc     = (float*)alloc(512 * 4);
  (void)ws_size; (void)in_sizes; (void)n_in; (void)out_size;

  // multi-split CSR build (by dst), no global atomics in the scatter
  hipMemsetAsync(bh, 0, NBK * 4, stream);
  ms_hist_kernel<<<NCH, 256, 0, stream>>>(ei, hist, bh, EE);
  bkt_scan_kernel<<<1, 256, 0, stream>>>(bh, boff, EE);
  ms_offs_kernel<<<(NBK + 255) / 256, 256, 0, stream>>>(hist, boff);
  ms_scatter_kernel<<<NCH, 256, 0, stream>>>(ei, hist, ebkt, EE);
  bkt_deg_kernel<<<NBK, 256, 0, stream>>>(ebkt, boff, deg, NN);
  scan1_kernel<<<98, 256, 0, stream>>>(deg, rowp, partial, NN);
  scan2_kernel<<<1, 256, 0, stream>>>(partial, 98);
  scan3_kernel<<<(NN + 255) / 256, 256, 0, stream>>>(rowp, partial, NN, EE);
  bkt_fill_kernel<<<NBK, 256, 0, stream>>>(ebkt, boff, rowp, colb, NN);

  // prep
  bnprep_kernel<<<2, 256, 0, stream>>>(b1, g1, be1, m1, v1, bL, gL, beL, mL, vL, sc, tc);
  wtprep_kernel<<<864, 256, 0, stream>>>(W1, WL, Wc1, Wcl, wt1, wtL, wtc1, wtcl);
  xconv_kernel<<<(NN * 16 + 255) / 256, 256, 0, stream>>>(x, bufA, NN);

  const int GB = (NN + 127) / 128;   // 782 node-tiles
  const int AGG_GRID = 25000 * 8;    // (tiles of 4 nodes) x 8 slices

  // GIN layer 1 (64 -> 128), double lrelu
  agg_kernel<64><<<AGG_GRID, 256, 0, stream>>>(bufA, rowp, colb, eps1, bufB, NN);
  gemm_kernel<64, 128, 8, 16, 2, true><<<dim3(GB, 1), 256, 0, stream>>>(bufB, wt1, sc, tc, bufA, NN);
  // GIN layers 2-4 (128 -> 128), double lrelu
  for (int i = 0; i < 3; ++i) {
    agg_kernel<128><<<AGG_GRID, 256, 0, stream>>>(bufA, rowp, colb, epsL + i, bufB, NN);
    gemm_kernel<128, 128, 16, 16, 2, true><<<dim3(GB, 1), 256, 0, stream>>>(
        bufB, wtL + i * 16384, sc + 128 * (i + 1), tc + 128 * (i + 1), bufA, NN);
  }
  // classifier: 128 -> 256 (no act), 2 x (256 -> 256, lrelu), 256 -> 1 sigmoid
  gemm_kernel<128, 256, 16, 0, 0, false><<<dim3(GB, 2), 256, 0, stream>>>(bufA, wtc1, nullptr, bc1, bufB, NN);
  gemm_kernel<256, 256, 0, 0, 1, false><<<dim3(GB, 2), 256, 0, stream>>>(bufB, wtcl, nullptr, bcl, bufA, NN);
  gemm_kernel<256, 256, 0, 0, 1, false><<<dim3(GB, 2), 256, 0, stream>>>(bufA, wtcl + 65536, nullptr, bcl + 256, bufB, NN);
  final_kernel<<<25000, 256, 0, stream>>>(bufB, Wf, bfp, out, NN);
}

// Round 8
// 708.188 us; speedup vs baseline: 1.5741x; 1.5741x over previous
//
#include <hip/hip_runtime.h>
#include <stdint.h>

// ---------------------------------------------------------------------------
// GIN (4 layers, CSR gather aggregation) + MLP classifier, bf16 MFMA GEMMs.
// R8 change: agg v4 — sliced + XCD-pinned (kept from R7: FETCH 188->41MB
//   proved locality) but wave-task count restored to 100K (R7's 800K tiny
//   tasks were overhead-bound: 213us, VALU 63%). Wave = 8 nodes x 1 slice
//   (LPN=8 lanes/node, 2ch/lane); group iterates its node's edges with 8
//   prefetched colb indices/round; no cross-group reduction (lane owns its
//   channels). C=64: LPN=4, 16 nodes/wave.
// ---------------------------------------------------------------------------

#define NN  100000
#define EE  1600000
#define CIN 64
#define CC  128
#define NBK 782              // ceil(NN / 128) buckets, bucket = dst >> 7
#define CHUNK 8192           // edges per multi-split block
#define NCH 196              // ceil(EE / CHUNK)

typedef __attribute__((ext_vector_type(8))) __bf16 bf16x8;
typedef __attribute__((ext_vector_type(4))) float  f32x4;

__device__ __forceinline__ float bf2f(uint32_t u) { return __uint_as_float(u << 16); }
__device__ __forceinline__ float bf2f_hi(uint32_t u) { return __uint_as_float(u & 0xffff0000u); }
__device__ __forceinline__ ushort f2bf(float f) {          // RNE f32 -> bf16
  uint32_t u = __float_as_uint(f);
  u += 0x7fffu + ((u >> 16) & 1u);
  return (ushort)(u >> 16);
}

template<int ACT> __device__ __forceinline__ float actf(float z) {
  if constexpr (ACT == 1) return z >= 0.f ? z : 0.01f * z;       // lrelu
  else if constexpr (ACT == 2) return z >= 0.f ? z : 1e-4f * z;  // lrelu(lrelu)
  else return z;
}

// ---------------- multi-split CSR build ----------------
__global__ __launch_bounds__(256) void ms_hist_kernel(const int* __restrict__ ei,
                                                      int* __restrict__ hist,
                                                      int* __restrict__ bh, int e) {
  __shared__ int h[NBK];
  for (int i = threadIdx.x; i < NBK; i += 256) h[i] = 0;
  __syncthreads();
  const int base = blockIdx.x * CHUNK;
  const int end = min(base + CHUNK, e);
  for (int i = base + threadIdx.x; i < end; i += 256)
    atomicAdd(&h[ei[e + i] >> 7], 1);
  __syncthreads();
  for (int i = threadIdx.x; i < NBK; i += 256) {
    hist[blockIdx.x * NBK + i] = h[i];
    if (h[i]) atomicAdd(&bh[i], h[i]);
  }
}

__global__ __launch_bounds__(256) void bkt_scan_kernel(const int* __restrict__ bh,
                                                       int* __restrict__ boff, int e) {
  __shared__ int sd[256];
  int t = threadIdx.x;
  int base = t * 4;
  int v0 = base + 0 < NBK ? bh[base + 0] : 0;
  int v1 = base + 1 < NBK ? bh[base + 1] : 0;
  int v2 = base + 2 < NBK ? bh[base + 2] : 0;
  int v3 = base + 3 < NBK ? bh[base + 3] : 0;
  int ts = v0 + v1 + v2 + v3;
  sd[t] = ts; __syncthreads();
  for (int off = 1; off < 256; off <<= 1) {
    int u = (t >= off) ? sd[t - off] : 0;
    __syncthreads();
    sd[t] += u;
    __syncthreads();
  }
  int excl = sd[t] - ts;
  if (base + 0 < NBK) boff[base + 0] = excl;
  if (base + 1 < NBK) boff[base + 1] = excl + v0;
  if (base + 2 < NBK) boff[base + 2] = excl + v0 + v1;
  if (base + 3 < NBK) boff[base + 3] = excl + v0 + v1 + v2;
  if (t == 255) boff[NBK] = e;
}

__global__ void ms_offs_kernel(int* __restrict__ hist, const int* __restrict__ boff) {
  int b = blockIdx.x * 256 + threadIdx.x;
  if (b >= NBK) return;
  int run = boff[b];
  for (int k = 0; k < NCH; ++k) {
    int t = hist[k * NBK + b];     // coalesced across b
    hist[k * NBK + b] = run;
    run += t;
  }
}

__global__ __launch_bounds__(256) void ms_scatter_kernel(const int* __restrict__ ei,
                                                         const int* __restrict__ hist,
                                                         uint* __restrict__ ebkt, int e) {
  __shared__ int cur[NBK];
  for (int i = threadIdx.x; i < NBK; i += 256) cur[i] = hist[blockIdx.x * NBK + i];
  __syncthreads();
  const int base = blockIdx.x * CHUNK;
  const int end = min(base + CHUNK, e);
  for (int i = base + threadIdx.x; i < end; i += 256) {
    int s = ei[i], d = ei[e + i];
    int p = atomicAdd(&cur[d >> 7], 1);
    ebkt[p] = ((uint)(d & 127) << 17) | (uint)s;
  }
}

__global__ __launch_bounds__(256) void bkt_deg_kernel(const uint* __restrict__ ebkt,
                                                      const int* __restrict__ boff,
                                                      int* __restrict__ deg, int n) {
  __shared__ int dl[128];
  int b = blockIdx.x;
  for (int i = threadIdx.x; i < 128; i += 256) dl[i] = 0;
  __syncthreads();
  int j1 = boff[b + 1];
  for (int j = boff[b] + threadIdx.x; j < j1; j += 256)
    atomicAdd(&dl[ebkt[j] >> 17], 1);
  __syncthreads();
  for (int i = threadIdx.x; i < 128; i += 256) {
    int node = (b << 7) + i;
    if (node < n) deg[node] = dl[i];
  }
}

__global__ __launch_bounds__(256) void bkt_fill_kernel(const uint* __restrict__ ebkt,
                                                       const int* __restrict__ boff,
                                                       const int* __restrict__ rowp,
                                                       int* __restrict__ colb, int n) {
  __shared__ int cur[128];
  int b = blockIdx.x;
  for (int i = threadIdx.x; i < 128; i += 256) {
    int node = (b << 7) + i;
    cur[i] = (node < n) ? rowp[node] : 0;
  }
  __syncthreads();
  int j1 = boff[b + 1];
  for (int j = boff[b] + threadIdx.x; j < j1; j += 256) {
    uint v = ebkt[j];
    int p = atomicAdd(&cur[v >> 17], 1);
    colb[p] = (int)(v & 0x1FFFFu);
  }
}

// ---------------- node-degree scan (rowp) ----------------
__global__ void scan1_kernel(const int* __restrict__ deg, int* __restrict__ outp,
                             int* __restrict__ partial, int n) {
  __shared__ int sd[256];
  int t = threadIdx.x;
  int base = blockIdx.x * 1024 + t * 4;
  int v0 = base + 0 < n ? deg[base + 0] : 0;
  int v1 = base + 1 < n ? deg[base + 1] : 0;
  int v2 = base + 2 < n ? deg[base + 2] : 0;
  int v3 = base + 3 < n ? deg[base + 3] : 0;
  int ts = v0 + v1 + v2 + v3;
  sd[t] = ts; __syncthreads();
  for (int off = 1; off < 256; off <<= 1) {
    int u = (t >= off) ? sd[t - off] : 0;
    __syncthreads();
    sd[t] += u;
    __syncthreads();
  }
  int excl = sd[t] - ts;
  if (base + 0 < n) outp[base + 0] = excl;
  if (base + 1 < n) outp[base + 1] = excl + v0;
  if (base + 2 < n) outp[base + 2] = excl + v0 + v1;
  if (base + 3 < n) outp[base + 3] = excl + v0 + v1 + v2;
  if (t == 255) partial[blockIdx.x] = sd[255];
}

__global__ void scan2_kernel(int* __restrict__ partial, int nb) {
  __shared__ int sd[256];
  int t = threadIdx.x;
  int v = t < nb ? partial[t] : 0;
  sd[t] = v; __syncthreads();
  for (int off = 1; off < 256; off <<= 1) {
    int u = (t >= off) ? sd[t - off] : 0;
    __syncthreads();
    sd[t] += u;
    __syncthreads();
  }
  if (t < nb) partial[t] = sd[t] - v;  // exclusive block offsets
}

__global__ void scan3_kernel(int* __restrict__ rowp, const int* __restrict__ partial,
                             int n, int e) {
  int i = blockIdx.x * 256 + threadIdx.x;
  if (i == 0) rowp[n] = e;
  if (i < n) rowp[i] += partial[i >> 10];
}

// ---------------- prep ----------------
__global__ void bnprep_kernel(const float* b1, const float* g1, const float* be1,
                              const float* m1, const float* v1,
                              const float* bL, const float* gL, const float* beL,
                              const float* mL, const float* vL,
                              float* __restrict__ sc, float* __restrict__ tc) {
  int i = blockIdx.x * 256 + threadIdx.x;
  if (i >= 4 * 128) return;
  int layer = i >> 7, c = i & 127;
  float b, g, be, m, v;
  if (layer == 0) { b = b1[c]; g = g1[c]; be = be1[c]; m = m1[c]; v = v1[c]; }
  else { int o = (layer - 1) * 128 + c; b = bL[o]; g = gL[o]; be = beL[o]; m = mL[o]; v = vL[o]; }
  float s = g * rsqrtf(v + 1e-5f);
  sc[i] = s;
  tc[i] = (b - m) * s + be;
}

// transpose fp32 weights -> bf16 Wt (M x K row-major)
__global__ void wtprep_kernel(const float* __restrict__ W1, const float* __restrict__ WL,
                              const float* __restrict__ Wc1, const float* __restrict__ Wcl,
                              ushort* __restrict__ wt1, ushort* __restrict__ wtL,
                              ushort* __restrict__ wtc1, ushort* __restrict__ wtcl) {
  int i = blockIdx.x * 256 + threadIdx.x;
  if (i < 8192) {                                      // W1: 64x128 -> 128x64
    int m = i >> 6, k = i & 63;
    wt1[i] = f2bf(W1[k * 128 + m]);
  } else if (i < 8192 + 49152) {                       // WL: 3 x 128x128
    int j = i - 8192;
    int l = j >> 14, r = j & 16383, m = r >> 7, k = r & 127;
    wtL[j] = f2bf(WL[l * 16384 + k * 128 + m]);
  } else if (i < 8192 + 49152 + 32768) {               // Wc1: 128x256 -> 256x128
    int j = i - (8192 + 49152);
    int m = j >> 7, k = j & 127;
    wtc1[j] = f2bf(Wc1[k * 256 + m]);
  } else if (i < 8192 + 49152 + 32768 + 131072) {      // Wcl: 2 x 256x256
    int j = i - (8192 + 49152 + 32768);
    int l = j >> 16, r = j & 65535, m = r >> 8, k = r & 255;
    wtcl[j] = f2bf(Wcl[l * 65536 + k * 256 + m]);
  }
}

// x fp32 [N][64] -> bf16 sliced8 [8][N][8]
__global__ void xconv_kernel(const float* __restrict__ x, ushort* __restrict__ xb, int n) {
  int i = blockIdx.x * 256 + threadIdx.x;
  if (i >= n * 16) return;
  int node = i >> 4, c4 = (i & 15) * 4;
  float4 v = *(const float4*)(x + (size_t)node * 64 + c4);
  ushort4 o;
  o.x = f2bf(v.x); o.y = f2bf(v.y); o.z = f2bf(v.z); o.w = f2bf(v.w);
  int sl = c4 >> 3, off = c4 & 7;
  *(ushort4*)(xb + (size_t)sl * ((size_t)NN * 8) + (size_t)node * 8 + off) = o;
}

// ---------------- aggregation v4: sliced, XCD-pinned, 8 nodes/wave ----------
// blockIdx.x%8 = slice (pins slice to one XCD's L2). Wave = NPW nodes;
// LPN lanes per node, lane owns 2 channels. Group iterates its node's edges:
// LPN colb indices prefetched per round, LPN predicated loads (independent).
template<int C>
__global__ __launch_bounds__(256) void agg_kernel(
    const ushort* __restrict__ hb,   // sliced [8][N][SW]
    const int* __restrict__ rowp,
    const int* __restrict__ colb, const float* __restrict__ ep,
    ushort* __restrict__ zout, int n)  // sliced [8][N][SW]
{
  constexpr int SW  = C / 8;           // slice width in channels (16 / 8)
  constexpr int LPN = SW / 2;          // lanes per node (8 / 4)
  constexpr int NPW = 64 / LPN;        // nodes per wave (8 / 16)
  constexpr int NPB = NPW * 4;         // nodes per block
  const int slice = blockIdx.x & 7;
  const int tile  = blockIdx.x >> 3;
  const int lane  = threadIdx.x & 63;
  const int wv    = threadIdx.x >> 6;
  const int lo    = lane & (LPN - 1);
  const int gb    = lane & ~(LPN - 1);     // group base lane
  const int node  = tile * NPB + wv * NPW + (lane / LPN);
  const float e1 = 1.0f + ep[0];
  const ushort* hs = hb + (size_t)slice * ((size_t)n * SW);
  ushort* zs = zout + (size_t)slice * ((size_t)n * SW);

  const bool valid = node < n;
  int j0 = 0, jend = 0;
  if (valid) { j0 = rowp[node]; jend = rowp[node + 1]; }

  float a0 = 0.f, a1 = 0.f;
  while (__any(j0 < jend)) {
    int idx = j0 + lo;
    int myn = (idx < jend) ? colb[idx] : 0;   // LPN coalesced ints per group
    #pragma unroll
    for (int i = 0; i < LPN; ++i) {
      int u = __shfl(myn, gb + i);
      if (j0 + i < jend) {
        uint v = *(const uint*)(hs + (size_t)u * SW + lo * 2);
        a0 += bf2f(v); a1 += bf2f_hi(v);
      }
    }
    j0 += LPN;
  }

  if (valid) {
    uint d = *(const uint*)(hs + (size_t)node * SW + lo * 2);
    uint o = (uint)f2bf(e1 * bf2f(d) + a0) | ((uint)f2bf(e1 * bf2f_hi(d) + a1) << 16);
    *(uint*)(zs + (size_t)node * SW + lo * 2) = o;
  }
}

// ---------------- GEMM v3: block = 128 nodes x 128 ch, waves split M --------
// XS/OS = slice width of X / output layout (0 = flat [N][K] / [N][M]).
template<int K, int M, int XS, int OS, int ACT, bool BN>
__global__ __launch_bounds__(256) void gemm_kernel(
    const ushort* __restrict__ xin,
    const ushort* __restrict__ wt,    // M x K  bf16 (row-major)
    const float*  __restrict__ sc,
    const float*  __restrict__ tc,
    ushort* __restrict__ hout,
    int n)
{
  constexpr int KS = 64;
  __shared__ ushort ldsW[128 * KS];   // 16 KiB, XOR-swizzled rows
  __shared__ ushort ldsX[128 * KS];   // 16 KiB, XOR-swizzled rows
  const int tid = threadIdx.x;
  const int wave = tid >> 6, lane = tid & 63;
  const int lr = lane & 15, lg = lane >> 4;
  const int n0 = blockIdx.x * 128;
  const int mB = blockIdx.y * 128;

  f32x4 acc[8][2];
  #pragma unroll
  for (int r = 0; r < 8; ++r) {
    acc[r][0] = (f32x4){0.f, 0.f, 0.f, 0.f};
    acc[r][1] = (f32x4){0.f, 0.f, 0.f, 0.f};
  }

  #pragma unroll
  for (int s = 0; s < K / KS; ++s) {
    if (s) __syncthreads();
    // stage W chunk: rows mB..mB+127, k slab s (128x64 bf16)
    #pragma unroll
    for (int c0 = 0; c0 < 1024; c0 += 256) {
      int c = c0 + tid;
      int m = c >> 3, kc = c & 7;
      uint4 v = *(const uint4*)(wt + (size_t)(mB + m) * K + s * KS + kc * 8);
      *(uint4*)((char*)ldsW + ((m * 128 + kc * 16) ^ ((m & 7) << 4))) = v;
    }
    // stage X tile: nodes n0..n0+127, k slab s
    #pragma unroll
    for (int c0 = 0; c0 < 1024; c0 += 256) {
      int c = c0 + tid;
      int r = c >> 3, kc = c & 7;
      int nd = n0 + r; if (nd >= n) nd = n - 1;
      const ushort* xp;
      if constexpr (XS == 0) {
        xp = xin + (size_t)nd * K + s * KS + kc * 8;
      } else {
        int ch = s * KS + kc * 8;
        int sl = ch / XS, off = ch % XS;
        xp = xin + (size_t)sl * ((size_t)NN * XS) + (size_t)nd * XS + off;
      }
      uint4 v = *(const uint4*)xp;
      *(uint4*)((char*)ldsX + ((r * 128 + kc * 16) ^ ((r & 7) << 4))) = v;
    }
    __syncthreads();
    #pragma unroll
    for (int k0 = 0; k0 < KS; k0 += 32) {
      const int kb = (k0 + lg * 8) * 2;  // byte offset of this lane's 16B in a row
      bf16x8 wf0, wf1;
      {
        int m = wave * 32 + lr;
        wf0 = __builtin_bit_cast(bf16x8,
              *(const uint4*)((const char*)ldsW + ((m * 128 + kb) ^ ((m & 7) << 4))));
        m += 16;
        wf1 = __builtin_bit_cast(bf16x8,
              *(const uint4*)((const char*)ldsW + ((m * 128 + kb) ^ ((m & 7) << 4))));
      }
      #pragma unroll
      for (int r = 0; r < 8; ++r) {
        int xr = r * 16 + lr;
        bf16x8 xf = __builtin_bit_cast(bf16x8,
              *(const uint4*)((const char*)ldsX + ((xr * 128 + kb) ^ ((xr & 7) << 4))));
        acc[r][0] = __builtin_amdgcn_mfma_f32_16x16x32_bf16(wf0, xf, acc[r][0], 0, 0, 0);
        acc[r][1] = __builtin_amdgcn_mfma_f32_16x16x32_bf16(wf1, xf, acc[r][1], 0, 0, 0);
      }
    }
  }

  // epilogue: D col = node (lane&15), D rows = 4*lg + reg (consecutive channels)
  #pragma unroll
  for (int ct = 0; ct < 2; ++ct) {
    const int c0 = mB + wave * 32 + ct * 16 + lg * 4;
    float4 sv;
    if constexpr (BN) sv = *(const float4*)(sc + c0);
    else sv = make_float4(1.f, 1.f, 1.f, 1.f);
    const float4 tv = *(const float4*)(tc + c0);
    #pragma unroll
    for (int r = 0; r < 8; ++r) {
      const int node = n0 + r * 16 + lr;
      if (node < n) {
        const f32x4 a = acc[r][ct];
        ushort4 o;
        o.x = f2bf(actf<ACT>(a[0] * sv.x + tv.x));
        o.y = f2bf(actf<ACT>(a[1] * sv.y + tv.y));
        o.z = f2bf(actf<ACT>(a[2] * sv.z + tv.z));
        o.w = f2bf(actf<ACT>(a[3] * sv.w + tv.w));
        ushort* hp;
        if constexpr (OS == 0) {
          hp = hout + (size_t)node * M + c0;
        } else {
          int sl = c0 / OS, off = c0 % OS;
          hp = hout + (size_t)sl * ((size_t)NN * OS) + (size_t)node * OS + off;
        }
        *(ushort4*)hp = o;
      }
    }
  }
}

// ---------------- final: sigmoid(s . Wf + bf) ----------------
__global__ __launch_bounds__(256) void final_kernel(
    const ushort* __restrict__ s, const float* __restrict__ wf,
    const float* __restrict__ bfp, float* __restrict__ out, int n)
{
  const int lane = threadIdx.x & 63;
  const int node = blockIdx.x * 4 + (threadIdx.x >> 6);
  if (node >= n) return;
  const uint2 d = *(const uint2*)(s + (size_t)node * 256 + lane * 4);
  const float4 w = *(const float4*)(wf + lane * 4);
  float acc = bf2f(d.x & 0xffff) * w.x + bf2f(d.x >> 16) * w.y
            + bf2f(d.y & 0xffff) * w.z + bf2f(d.y >> 16) * w.w;
  for (int off = 32; off; off >>= 1) acc += __shfl_down(acc, off);
  if (lane == 0) out[node] = 1.f / (1.f + expf(-(acc + bfp[0])));
}

// ---------------- launch ----------------
extern "C" void kernel_launch(void* const* d_in, const int* in_sizes, int n_in,
                              void* d_out, int out_size, void* d_ws, size_t ws_size,
                              hipStream_t stream)
{
  const float* x    = (const float*)d_in[0];
  const int*   ei   = (const int*)d_in[1];
  const float* eps1 = (const float*)d_in[3];
  const float* W1   = (const float*)d_in[4];
  const float* b1   = (const float*)d_in[5];
  const float* g1   = (const float*)d_in[6];
  const float* be1  = (const float*)d_in[7];
  const float* m1   = (const float*)d_in[8];
  const float* v1   = (const float*)d_in[9];
  const float* epsL = (const float*)d_in[10];
  const float* WL   = (const float*)d_in[11];
  const float* bL   = (const float*)d_in[12];
  const float* gL   = (const float*)d_in[13];
  const float* beL  = (const float*)d_in[14];
  const float* mL   = (const float*)d_in[15];
  const float* vL   = (const float*)d_in[16];
  const float* Wc1  = (const float*)d_in[17];
  const float* bc1  = (const float*)d_in[18];
  const float* Wcl  = (const float*)d_in[19];
  const float* bcl  = (const float*)d_in[20];
  const float* Wf   = (const float*)d_in[21];
  const float* bfp  = (const float*)d_in[22];
  float* out = (float*)d_out;

  char* w = (char*)d_ws;
  size_t off = 0;
  auto alloc = [&](size_t bytes) {
    char* p = w + off;
    off += (bytes + 255) & ~(size_t)255;
    return p;
  };
  ushort* bufA   = (ushort*)alloc((size_t)NN * 256 * 2);   // 51.2 MB
  ushort* bufB   = (ushort*)alloc((size_t)NN * 256 * 2);   // 51.2 MB
  int*    rowp   = (int*)alloc((NN + 1) * 4);
  int*    deg    = (int*)alloc(NN * 4);
  int*    colb   = (int*)alloc((size_t)EE * 4);
  uint*   ebkt   = (uint*)alloc((size_t)EE * 4);
  int*    hist   = (int*)alloc((size_t)NCH * NBK * 4);     // 613 KB
  int*    bh     = (int*)alloc(NBK * 4);
  int*    boff   = (int*)alloc((NBK + 1) * 4);
  int*    partial= (int*)alloc(1024);
  ushort* wt1    = (ushort*)alloc(8192 * 2);
  ushort* wtL    = (ushort*)alloc(49152 * 2);
  ushort* wtc1   = (ushort*)alloc(32768 * 2);
  ushort* wtcl   = (ushort*)alloc(131072 * 2);
  float*  sc     = (float*)alloc(512 * 4);
  float*  tc     = (float*)alloc(512 * 4);
  (void)ws_size; (void)in_sizes; (void)n_in; (void)out_size;

  // multi-split CSR build (by dst), no global atomics in the scatter
  hipMemsetAsync(bh, 0, NBK * 4, stream);
  ms_hist_kernel<<<NCH, 256, 0, stream>>>(ei, hist, bh, EE);
  bkt_scan_kernel<<<1, 256, 0, stream>>>(bh, boff, EE);
  ms_offs_kernel<<<(NBK + 255) / 256, 256, 0, stream>>>(hist, boff);
  ms_scatter_kernel<<<NCH, 256, 0, stream>>>(ei, hist, ebkt, EE);
  bkt_deg_kernel<<<NBK, 256, 0, stream>>>(ebkt, boff, deg, NN);
  scan1_kernel<<<98, 256, 0, stream>>>(deg, rowp, partial, NN);
  scan2_kernel<<<1, 256, 0, stream>>>(partial, 98);
  scan3_kernel<<<(NN + 255) / 256, 256, 0, stream>>>(rowp, partial, NN, EE);
  bkt_fill_kernel<<<NBK, 256, 0, stream>>>(ebkt, boff, rowp, colb, NN);

  // prep
  bnprep_kernel<<<2, 256, 0, stream>>>(b1, g1, be1, m1, v1, bL, gL, beL, mL, vL, sc, tc);
  wtprep_kernel<<<864, 256, 0, stream>>>(W1, WL, Wc1, Wcl, wt1, wtL, wtc1, wtcl);
  xconv_kernel<<<(NN * 16 + 255) / 256, 256, 0, stream>>>(x, bufA, NN);

  const int GB = (NN + 127) / 128;   // 782 node-tiles
  // agg grids: C=128 -> 32 nodes/block, C=64 -> 64 nodes/block; x8 slices
  const int AGG128 = ((NN + 31) / 32) * 8;   // 3125*8 = 25000
  const int AGG64  = ((NN + 63) / 64) * 8;   // 1563*8 = 12504

  // GIN layer 1 (64 -> 128), double lrelu
  agg_kernel<64><<<AGG64, 256, 0, stream>>>(bufA, rowp, colb, eps1, bufB, NN);
  gemm_kernel<64, 128, 8, 16, 2, true><<<dim3(GB, 1), 256, 0, stream>>>(bufB, wt1, sc, tc, bufA, NN);
  // GIN layers 2-4 (128 -> 128), double lrelu
  for (int i = 0; i < 3; ++i) {
    agg_kernel<128><<<AGG128, 256, 0, stream>>>(bufA, rowp, colb, epsL + i, bufB, NN);
    gemm_kernel<128, 128, 16, 16, 2, true><<<dim3(GB, 1), 256, 0, stream>>>(
        bufB, wtL + i * 16384, sc + 128 * (i + 1), tc + 128 * (i + 1), bufA, NN);
  }
  // classifier: 128 -> 256 (no act), 2 x (256 -> 256, lrelu), 256 -> 1 sigmoid
  gemm_kernel<128, 256, 16, 0, 0, false><<<dim3(GB, 2), 256, 0, stream>>>(bufA, wtc1, nullptr, bc1, bufB, NN);
  gemm_kernel<256, 256, 0, 0, 1, false><<<dim3(GB, 2), 256, 0, stream>>>(bufB, wtcl, nullptr, bcl, bufA, NN);
  gemm_kernel<256, 256, 0, 0, 1, false><<<dim3(GB, 2), 256, 0, stream>>>(bufA, wtcl + 65536, nullptr, bcl + 256, bufB, NN);
  final_kernel<<<25000, 256, 0, stream>>>(bufB, Wf, bfp, out, NN);
}

// Round 9
// 510.470 us; speedup vs baseline: 2.1838x; 1.3873x over previous
//
#include <hip/hip_runtime.h>
#include <stdint.h>

// ---------------------------------------------------------------------------
// GIN (4 layers, CSR gather aggregation) + MLP classifier, bf16 MFMA GEMMs.
// R9 changes:
//   - agg reverted to R5 flat wide-gather (measured 63us; sliced variants were
//     instruction-overhead-bound: R7 213us, R8 108us despite FETCH 188->48MB.
//     Flat agg is at the HBM random-gather ceiling ~3.45 TB/s).
//   - GEMM v4: v3 tiling + global_load_lds(16B) staging. LDS linear, global
//     SOURCE pre-swizzled with the read-side XOR ((m&7)<<4 within 128B row),
//     so ds_read fragments stay conflict-free. 8 staging instrs/wave/slab vs
//     64 before. Explicit s_waitcnt vmcnt(0) before the barrier.
// ---------------------------------------------------------------------------

#define NN  100000
#define EE  1600000
#define CIN 64
#define CC  128
#define NBK 782              // ceil(NN / 128) buckets, bucket = dst >> 7
#define CHUNK 8192           // edges per multi-split block
#define NCH 196              // ceil(EE / CHUNK)

typedef __attribute__((ext_vector_type(8))) __bf16 bf16x8;
typedef __attribute__((ext_vector_type(4))) float  f32x4;

__device__ __forceinline__ float bf2f(uint32_t u) { return __uint_as_float(u << 16); }
__device__ __forceinline__ float bf2f_hi(uint32_t u) { return __uint_as_float(u & 0xffff0000u); }
__device__ __forceinline__ ushort f2bf(float f) {          // RNE f32 -> bf16
  uint32_t u = __float_as_uint(f);
  u += 0x7fffu + ((u >> 16) & 1u);
  return (ushort)(u >> 16);
}

template<int ACT> __device__ __forceinline__ float actf(float z) {
  if constexpr (ACT == 1) return z >= 0.f ? z : 0.01f * z;       // lrelu
  else if constexpr (ACT == 2) return z >= 0.f ? z : 1e-4f * z;  // lrelu(lrelu)
  else return z;
}

// async global->LDS, 16B per lane; lds base must be wave-uniform
__device__ __forceinline__ void gload_lds16(const void* g, void* l) {
  __builtin_amdgcn_global_load_lds(
      (const __attribute__((address_space(1))) void*)g,
      (__attribute__((address_space(3))) void*)l, 16, 0, 0);
}

// ---------------- multi-split CSR build ----------------
__global__ __launch_bounds__(256) void ms_hist_kernel(const int* __restrict__ ei,
                                                      int* __restrict__ hist,
                                                      int* __restrict__ bh, int e) {
  __shared__ int h[NBK];
  for (int i = threadIdx.x; i < NBK; i += 256) h[i] = 0;
  __syncthreads();
  const int base = blockIdx.x * CHUNK;
  const int end = min(base + CHUNK, e);
  for (int i = base + threadIdx.x; i < end; i += 256)
    atomicAdd(&h[ei[e + i] >> 7], 1);
  __syncthreads();
  for (int i = threadIdx.x; i < NBK; i += 256) {
    hist[blockIdx.x * NBK + i] = h[i];
    if (h[i]) atomicAdd(&bh[i], h[i]);
  }
}

__global__ __launch_bounds__(256) void bkt_scan_kernel(const int* __restrict__ bh,
                                                       int* __restrict__ boff, int e) {
  __shared__ int sd[256];
  int t = threadIdx.x;
  int base = t * 4;
  int v0 = base + 0 < NBK ? bh[base + 0] : 0;
  int v1 = base + 1 < NBK ? bh[base + 1] : 0;
  int v2 = base + 2 < NBK ? bh[base + 2] : 0;
  int v3 = base + 3 < NBK ? bh[base + 3] : 0;
  int ts = v0 + v1 + v2 + v3;
  sd[t] = ts; __syncthreads();
  for (int off = 1; off < 256; off <<= 1) {
    int u = (t >= off) ? sd[t - off] : 0;
    __syncthreads();
    sd[t] += u;
    __syncthreads();
  }
  int excl = sd[t] - ts;
  if (base + 0 < NBK) boff[base + 0] = excl;
  if (base + 1 < NBK) boff[base + 1] = excl + v0;
  if (base + 2 < NBK) boff[base + 2] = excl + v0 + v1;
  if (base + 3 < NBK) boff[base + 3] = excl + v0 + v1 + v2;
  if (t == 255) boff[NBK] = e;
}

__global__ void ms_offs_kernel(int* __restrict__ hist, const int* __restrict__ boff) {
  int b = blockIdx.x * 256 + threadIdx.x;
  if (b >= NBK) return;
  int run = boff[b];
  for (int k = 0; k < NCH; ++k) {
    int t = hist[k * NBK + b];     // coalesced across b
    hist[k * NBK + b] = run;
    run += t;
  }
}

__global__ __launch_bounds__(256) void ms_scatter_kernel(const int* __restrict__ ei,
                                                         const int* __restrict__ hist,
                                                         uint* __restrict__ ebkt, int e) {
  __shared__ int cur[NBK];
  for (int i = threadIdx.x; i < NBK; i += 256) cur[i] = hist[blockIdx.x * NBK + i];
  __syncthreads();
  const int base = blockIdx.x * CHUNK;
  const int end = min(base + CHUNK, e);
  for (int i = base + threadIdx.x; i < end; i += 256) {
    int s = ei[i], d = ei[e + i];
    int p = atomicAdd(&cur[d >> 7], 1);
    ebkt[p] = ((uint)(d & 127) << 17) | (uint)s;
  }
}

__global__ __launch_bounds__(256) void bkt_deg_kernel(const uint* __restrict__ ebkt,
                                                      const int* __restrict__ boff,
                                                      int* __restrict__ deg, int n) {
  __shared__ int dl[128];
  int b = blockIdx.x;
  for (int i = threadIdx.x; i < 128; i += 256) dl[i] = 0;
  __syncthreads();
  int j1 = boff[b + 1];
  for (int j = boff[b] + threadIdx.x; j < j1; j += 256)
    atomicAdd(&dl[ebkt[j] >> 17], 1);
  __syncthreads();
  for (int i = threadIdx.x; i < 128; i += 256) {
    int node = (b << 7) + i;
    if (node < n) deg[node] = dl[i];
  }
}

__global__ __launch_bounds__(256) void bkt_fill_kernel(const uint* __restrict__ ebkt,
                                                       const int* __restrict__ boff,
                                                       const int* __restrict__ rowp,
                                                       int* __restrict__ colb, int n) {
  __shared__ int cur[128];
  int b = blockIdx.x;
  for (int i = threadIdx.x; i < 128; i += 256) {
    int node = (b << 7) + i;
    cur[i] = (node < n) ? rowp[node] : 0;
  }
  __syncthreads();
  int j1 = boff[b + 1];
  for (int j = boff[b] + threadIdx.x; j < j1; j += 256) {
    uint v = ebkt[j];
    int p = atomicAdd(&cur[v >> 17], 1);
    colb[p] = (int)(v & 0x1FFFFu);
  }
}

// ---------------- node-degree scan (rowp) ----------------
__global__ void scan1_kernel(const int* __restrict__ deg, int* __restrict__ outp,
                             int* __restrict__ partial, int n) {
  __shared__ int sd[256];
  int t = threadIdx.x;
  int base = blockIdx.x * 1024 + t * 4;
  int v0 = base + 0 < n ? deg[base + 0] : 0;
  int v1 = base + 1 < n ? deg[base + 1] : 0;
  int v2 = base + 2 < n ? deg[base + 2] : 0;
  int v3 = base + 3 < n ? deg[base + 3] : 0;
  int ts = v0 + v1 + v2 + v3;
  sd[t] = ts; __syncthreads();
  for (int off = 1; off < 256; off <<= 1) {
    int u = (t >= off) ? sd[t - off] : 0;
    __syncthreads();
    sd[t] += u;
    __syncthreads();
  }
  int excl = sd[t] - ts;
  if (base + 0 < n) outp[base + 0] = excl;
  if (base + 1 < n) outp[base + 1] = excl + v0;
  if (base + 2 < n) outp[base + 2] = excl + v0 + v1;
  if (base + 3 < n) outp[base + 3] = excl + v0 + v1 + v2;
  if (t == 255) partial[blockIdx.x] = sd[255];
}

__global__ void scan2_kernel(int* __restrict__ partial, int nb) {
  __shared__ int sd[256];
  int t = threadIdx.x;
  int v = t < nb ? partial[t] : 0;
  sd[t] = v; __syncthreads();
  for (int off = 1; off < 256; off <<= 1) {
    int u = (t >= off) ? sd[t - off] : 0;
    __syncthreads();
    sd[t] += u;
    __syncthreads();
  }
  if (t < nb) partial[t] = sd[t] - v;  // exclusive block offsets
}

__global__ void scan3_kernel(int* __restrict__ rowp, const int* __restrict__ partial,
                             int n, int e) {
  int i = blockIdx.x * 256 + threadIdx.x;
  if (i == 0) rowp[n] = e;
  if (i < n) rowp[i] += partial[i >> 10];
}

// ---------------- prep ----------------
__global__ void bnprep_kernel(const float* b1, const float* g1, const float* be1,
                              const float* m1, const float* v1,
                              const float* bL, const float* gL, const float* beL,
                              const float* mL, const float* vL,
                              float* __restrict__ sc, float* __restrict__ tc) {
  int i = blockIdx.x * 256 + threadIdx.x;
  if (i >= 4 * 128) return;
  int layer = i >> 7, c = i & 127;
  float b, g, be, m, v;
  if (layer == 0) { b = b1[c]; g = g1[c]; be = be1[c]; m = m1[c]; v = v1[c]; }
  else { int o = (layer - 1) * 128 + c; b = bL[o]; g = gL[o]; be = beL[o]; m = mL[o]; v = vL[o]; }
  float s = g * rsqrtf(v + 1e-5f);
  sc[i] = s;
  tc[i] = (b - m) * s + be;
}

// transpose fp32 weights -> bf16 Wt (M x K row-major)
__global__ void wtprep_kernel(const float* __restrict__ W1, const float* __restrict__ WL,
                              const float* __restrict__ Wc1, const float* __restrict__ Wcl,
                              ushort* __restrict__ wt1, ushort* __restrict__ wtL,
                              ushort* __restrict__ wtc1, ushort* __restrict__ wtcl) {
  int i = blockIdx.x * 256 + threadIdx.x;
  if (i < 8192) {                                      // W1: 64x128 -> 128x64
    int m = i >> 6, k = i & 63;
    wt1[i] = f2bf(W1[k * 128 + m]);
  } else if (i < 8192 + 49152) {                       // WL: 3 x 128x128
    int j = i - 8192;
    int l = j >> 14, r = j & 16383, m = r >> 7, k = r & 127;
    wtL[j] = f2bf(WL[l * 16384 + k * 128 + m]);
  } else if (i < 8192 + 49152 + 32768) {               // Wc1: 128x256 -> 256x128
    int j = i - (8192 + 49152);
    int m = j >> 7, k = j & 127;
    wtc1[j] = f2bf(Wc1[k * 256 + m]);
  } else if (i < 8192 + 49152 + 32768 + 131072) {      // Wcl: 2 x 256x256
    int j = i - (8192 + 49152 + 32768);
    int l = j >> 16, r = j & 65535, m = r >> 8, k = r & 255;
    wtcl[j] = f2bf(Wcl[l * 65536 + k * 256 + m]);
  }
}

// x fp32 [N][64] -> bf16 flat [N][64]
__global__ void xconv_kernel(const float* __restrict__ x, ushort* __restrict__ xb, int n4) {
  int i = blockIdx.x * 256 + threadIdx.x;
  if (i < n4) {
    float4 v = ((const float4*)x)[i];
    ushort4 o;
    o.x = f2bf(v.x); o.y = f2bf(v.y); o.z = f2bf(v.z); o.w = f2bf(v.w);
    ((ushort4*)xb)[i] = o;
  }
}

// ---------------- aggregation (R5 flat wide-gather): zin = (1+eps)*h + sum ----
template<int C>
__global__ __launch_bounds__(256) void agg_kernel(
    const ushort* __restrict__ hb, const int* __restrict__ rowp,
    const int* __restrict__ colb, const float* __restrict__ ep,
    ushort* __restrict__ zout, int n)
{
  constexpr int LPE = C / 8;     // lanes per edge (16 for C=128, 8 for C=64)
  constexpr int EPR = 64 / LPE;  // edges per round (4 or 8)
  const int lane = threadIdx.x & 63;
  const int node = blockIdx.x * 4 + (threadIdx.x >> 6);
  if (node >= n) return;
  const float e1 = 1.0f + ep[0];
  const int lo = lane & (LPE - 1);
  const int g  = lane / LPE;
  int j0 = rowp[node], jend = rowp[node + 1];

  float a0 = 0.f, a1 = 0.f, a2 = 0.f, a3 = 0.f,
        a4 = 0.f, a5 = 0.f, a6 = 0.f, a7 = 0.f;

  for (; j0 < jend; j0 += 64) {
    int cnt = jend - j0; if (cnt > 64) cnt = 64;
    int myn = (lane < cnt) ? colb[j0 + lane] : 0;
    int rounds = (cnt + EPR - 1) / EPR;
    #pragma unroll 4
    for (int r = 0; r < rounds; ++r) {
      int e = r * EPR + g;
      int u = __shfl(myn, e);          // all lanes active for the shuffle
      if (e < cnt) {
        const uint4 v = *(const uint4*)(hb + (size_t)u * C + lo * 8);
        a0 += bf2f(v.x); a1 += bf2f_hi(v.x);
        a2 += bf2f(v.y); a3 += bf2f_hi(v.y);
        a4 += bf2f(v.z); a5 += bf2f_hi(v.z);
        a6 += bf2f(v.w); a7 += bf2f_hi(v.w);
      }
    }
  }

  // combine group partials
  #pragma unroll
  for (int s = LPE; s < 64; s <<= 1) {
    a0 += __shfl_xor(a0, s); a1 += __shfl_xor(a1, s);
    a2 += __shfl_xor(a2, s); a3 += __shfl_xor(a3, s);
    a4 += __shfl_xor(a4, s); a5 += __shfl_xor(a5, s);
    a6 += __shfl_xor(a6, s); a7 += __shfl_xor(a7, s);
  }

  if (g == 0) {
    const uint4 d = *(const uint4*)(hb + (size_t)node * C + lo * 8);
    uint4 o;
    o.x = (uint)f2bf(e1 * bf2f(d.x) + a0) | ((uint)f2bf(e1 * bf2f_hi(d.x) + a1) << 16);
    o.y = (uint)f2bf(e1 * bf2f(d.y) + a2) | ((uint)f2bf(e1 * bf2f_hi(d.y) + a3) << 16);
    o.z = (uint)f2bf(e1 * bf2f(d.z) + a4) | ((uint)f2bf(e1 * bf2f_hi(d.z) + a5) << 16);
    o.w = (uint)f2bf(e1 * bf2f(d.w) + a6) | ((uint)f2bf(e1 * bf2f_hi(d.w) + a7) << 16);
    *(uint4*)(zout + (size_t)node * C + lo * 8) = o;
  }
}

// ---------------- GEMM v4: 128 nodes x 128 ch, global_load_lds staging -------
// LDS linear, global source pre-swizzled with the read-side XOR.
template<int K, int M, int ACT, bool BN>
__global__ __launch_bounds__(256) void gemm_kernel(
    const ushort* __restrict__ xin,   // N x K  bf16
    const ushort* __restrict__ wt,    // M x K  bf16 (row-major)
    const float*  __restrict__ sc,
    const float*  __restrict__ tc,
    ushort* __restrict__ hout,        // N x M  bf16
    int n)
{
  constexpr int KS = 64;
  __shared__ ushort ldsW[128 * KS];   // 16 KiB
  __shared__ ushort ldsX[128 * KS];   // 16 KiB
  const int tid = threadIdx.x;
  const int wave = tid >> 6, lane = tid & 63;
  const int lr = lane & 15, lg = lane >> 4;
  const int n0 = blockIdx.x * 128;
  const int mB = blockIdx.y * 128;

  f32x4 acc[8][2];
  #pragma unroll
  for (int r = 0; r < 8; ++r) {
    acc[r][0] = (f32x4){0.f, 0.f, 0.f, 0.f};
    acc[r][1] = (f32x4){0.f, 0.f, 0.f, 0.f};
  }

  #pragma unroll
  for (int s = 0; s < K / KS; ++s) {
    if (s) __syncthreads();           // previous reads done before overwrite
    // stage W+X via global_load_lds: wave covers bytes [wave*4K, wave*4K+4K)
    #pragma unroll
    for (int i = 0; i < 4; ++i) {
      const int ub = wave * 4096 + i * 1024;       // wave-uniform lds byte base
      const int a  = ub + lane * 16;               // this lane's lds byte
      const int m  = a >> 7;                       // row (128B rows)
      const int o  = (a & 127) ^ ((m & 7) << 4);   // pre-swizzled src offset
      // W row m of this M-block, k-slab s
      gload_lds16((const char*)wt + ((size_t)(mB + m) * K) * 2 + s * 128 + o,
                  (char*)ldsW + ub);
      // X row = node n0+m (clamped), k-slab s
      int nd = n0 + m; if (nd >= n) nd = n - 1;
      gload_lds16((const char*)xin + ((size_t)nd * K) * 2 + s * 128 + o,
                  (char*)ldsX + ub);
    }
    asm volatile("s_waitcnt vmcnt(0)" ::: "memory");
    __syncthreads();
    #pragma unroll
    for (int k0 = 0; k0 < KS; k0 += 32) {
      const int kb = (k0 + lg * 8) * 2;  // byte offset of this lane's 16B in a row
      bf16x8 wf0, wf1;
      {
        int m = wave * 32 + lr;
        wf0 = __builtin_bit_cast(bf16x8,
              *(const uint4*)((const char*)ldsW + ((m * 128 + kb) ^ ((m & 7) << 4))));
        m += 16;
        wf1 = __builtin_bit_cast(bf16x8,
              *(const uint4*)((const char*)ldsW + ((m * 128 + kb) ^ ((m & 7) << 4))));
      }
      #pragma unroll
      for (int r = 0; r < 8; ++r) {
        int xr = r * 16 + lr;
        bf16x8 xf = __builtin_bit_cast(bf16x8,
              *(const uint4*)((const char*)ldsX + ((xr * 128 + kb) ^ ((xr & 7) << 4))));
        acc[r][0] = __builtin_amdgcn_mfma_f32_16x16x32_bf16(wf0, xf, acc[r][0], 0, 0, 0);
        acc[r][1] = __builtin_amdgcn_mfma_f32_16x16x32_bf16(wf1, xf, acc[r][1], 0, 0, 0);
      }
    }
  }

  // epilogue: D col = node (lane&15), D rows = 4*lg + reg (consecutive channels)
  #pragma unroll
  for (int ct = 0; ct < 2; ++ct) {
    const int c0 = mB + wave * 32 + ct * 16 + lg * 4;
    float4 sv;
    if constexpr (BN) sv = *(const float4*)(sc + c0);
    else sv = make_float4(1.f, 1.f, 1.f, 1.f);
    const float4 tv = *(const float4*)(tc + c0);
    #pragma unroll
    for (int r = 0; r < 8; ++r) {
      const int node = n0 + r * 16 + lr;
      if (node < n) {
        const f32x4 a = acc[r][ct];
        ushort4 o;
        o.x = f2bf(actf<ACT>(a[0] * sv.x + tv.x));
        o.y = f2bf(actf<ACT>(a[1] * sv.y + tv.y));
        o.z = f2bf(actf<ACT>(a[2] * sv.z + tv.z));
        o.w = f2bf(actf<ACT>(a[3] * sv.w + tv.w));
        *(ushort4*)(hout + (size_t)node * M + c0) = o;
      }
    }
  }
}

// ---------------- final: sigmoid(s . Wf + bf) ----------------
__global__ __launch_bounds__(256) void final_kernel(
    const ushort* __restrict__ s, const float* __restrict__ wf,
    const float* __restrict__ bfp, float* __restrict__ out, int n)
{
  const int lane = threadIdx.x & 63;
  const int node = blockIdx.x * 4 + (threadIdx.x >> 6);
  if (node >= n) return;
  const uint2 d = *(const uint2*)(s + (size_t)node * 256 + lane * 4);
  const float4 w = *(const float4*)(wf + lane * 4);
  float acc = bf2f(d.x & 0xffff) * w.x + bf2f(d.x >> 16) * w.y
            + bf2f(d.y & 0xffff) * w.z + bf2f(d.y >> 16) * w.w;
  for (int off = 32; off; off >>= 1) acc += __shfl_down(acc, off);
  if (lane == 0) out[node] = 1.f / (1.f + expf(-(acc + bfp[0])));
}

// ---------------- launch ----------------
extern "C" void kernel_launch(void* const* d_in, const int* in_sizes, int n_in,
                              void* d_out, int out_size, void* d_ws, size_t ws_size,
                              hipStream_t stream)
{
  const float* x    = (const float*)d_in[0];
  const int*   ei   = (const int*)d_in[1];
  const float* eps1 = (const float*)d_in[3];
  const float* W1   = (const float*)d_in[4];
  const float* b1   = (const float*)d_in[5];
  const float* g1   = (const float*)d_in[6];
  const float* be1  = (const float*)d_in[7];
  const float* m1   = (const float*)d_in[8];
  const float* v1   = (const float*)d_in[9];
  const float* epsL = (const float*)d_in[10];
  const float* WL   = (const float*)d_in[11];
  const float* bL   = (const float*)d_in[12];
  const float* gL   = (const float*)d_in[13];
  const float* beL  = (const float*)d_in[14];
  const float* mL   = (const float*)d_in[15];
  const float* vL   = (const float*)d_in[16];
  const float* Wc1  = (const float*)d_in[17];
  const float* bc1  = (const float*)d_in[18];
  const float* Wcl  = (const float*)d_in[19];
  const float* bcl  = (const float*)d_in[20];
  const float* Wf   = (const float*)d_in[21];
  const float* bfp  = (const float*)d_in[22];
  float* out = (float*)d_out;

  char* w = (char*)d_ws;
  size_t off = 0;
  auto alloc = [&](size_t bytes) {
    char* p = w + off;
    off += (bytes + 255) & ~(size_t)255;
    return p;
  };
  ushort* bufA   = (ushort*)alloc((size_t)NN * 256 * 2);   // 51.2 MB
  ushort* bufB   = (ushort*)alloc((size_t)NN * 256 * 2);   // 51.2 MB
  int*    rowp   = (int*)alloc((NN + 1) * 4);
  int*    deg    = (int*)alloc(NN * 4);
  int*    colb   = (int*)alloc((size_t)EE * 4);
  uint*   ebkt   = (uint*)alloc((size_t)EE * 4);
  int*    hist   = (int*)alloc((size_t)NCH * NBK * 4);     // 613 KB
  int*    bh     = (int*)alloc(NBK * 4);
  int*    boff   = (int*)alloc((NBK + 1) * 4);
  int*    partial= (int*)alloc(1024);
  ushort* wt1    = (ushort*)alloc(8192 * 2);
  ushort* wtL    = (ushort*)alloc(49152 * 2);
  ushort* wtc1   = (ushort*)alloc(32768 * 2);
  ushort* wtcl   = (ushort*)alloc(131072 * 2);
  float*  sc     = (float*)alloc(512 * 4);
  float*  tc     = (float*)alloc(512 * 4);
  (void)ws_size; (void)in_sizes; (void)n_in; (void)out_size;

  // multi-split CSR build (by dst), no global atomics in the scatter
  hipMemsetAsync(bh, 0, NBK * 4, stream);
  ms_hist_kernel<<<NCH, 256, 0, stream>>>(ei, hist, bh, EE);
  bkt_scan_kernel<<<1, 256, 0, stream>>>(bh, boff, EE);
  ms_offs_kernel<<<(NBK + 255) / 256, 256, 0, stream>>>(hist, boff);
  ms_scatter_kernel<<<NCH, 256, 0, stream>>>(ei, hist, ebkt, EE);
  bkt_deg_kernel<<<NBK, 256, 0, stream>>>(ebkt, boff, deg, NN);
  scan1_kernel<<<98, 256, 0, stream>>>(deg, rowp, partial, NN);
  scan2_kernel<<<1, 256, 0, stream>>>(partial, 98);
  scan3_kernel<<<(NN + 255) / 256, 256, 0, stream>>>(rowp, partial, NN, EE);
  bkt_fill_kernel<<<NBK, 256, 0, stream>>>(ebkt, boff, rowp, colb, NN);

  // prep
  bnprep_kernel<<<2, 256, 0, stream>>>(b1, g1, be1, m1, v1, bL, gL, beL, mL, vL, sc, tc);
  wtprep_kernel<<<864, 256, 0, stream>>>(W1, WL, Wc1, Wcl, wt1, wtL, wtc1, wtcl);
  xconv_kernel<<<(NN * CIN / 4 + 255) / 256, 256, 0, stream>>>(x, bufA, NN * CIN / 4);

  const int GB = (NN + 127) / 128;   // 782 node-tiles

  // GIN layer 1 (64 -> 128), double lrelu
  agg_kernel<64><<<25000, 256, 0, stream>>>(bufA, rowp, colb, eps1, bufB, NN);
  gemm_kernel<64, 128, 2, true><<<dim3(GB, 1), 256, 0, stream>>>(bufB, wt1, sc, tc, bufA, NN);
  // GIN layers 2-4 (128 -> 128), double lrelu
  for (int i = 0; i < 3; ++i) {
    agg_kernel<128><<<25000, 256, 0, stream>>>(bufA, rowp, colb, epsL + i, bufB, NN);
    gemm_kernel<128, 128, 2, true><<<dim3(GB, 1), 256, 0, stream>>>(
        bufB, wtL + i * 16384, sc + 128 * (i + 1), tc + 128 * (i + 1), bufA, NN);
  }
  // classifier: 128 -> 256 (no act), 2 x (256 -> 256, lrelu), 256 -> 1 sigmoid
  gemm_kernel<128, 256, 0, false><<<dim3(GB, 2), 256, 0, stream>>>(bufA, wtc1, nullptr, bc1, bufB, NN);
  gemm_kernel<256, 256, 1, false><<<dim3(GB, 2), 256, 0, stream>>>(bufB, wtcl, nullptr, bcl, bufA, NN);
  gemm_kernel<256, 256, 1, false><<<dim3(GB, 2), 256, 0, stream>>>(bufA, wtcl + 65536, nullptr, bcl + 256, bufB, NN);
  final_kernel<<<25000, 256, 0, stream>>>(bufB, Wf, bfp, out, NN);
}

// Round 13
// 476.390 us; speedup vs baseline: 2.3401x; 1.0715x over previous
//
#include <hip/hip_runtime.h>
#include <stdint.h>

// ---------------------------------------------------------------------------
// GIN (4 layers, CSR gather aggregation) + MLP classifier, bf16 MFMA GEMMs.
// R10-R13: classifier fully fused into one kernel (cls_kernel).
//   Before: c1(128->256) + c2,c3(256->256) + final were 4 dispatches, each
//   round-tripping a 51.2MB bf16 intermediate through the ~3.4TB/s L2-miss
//   path. Now: block = 128 nodes, 144KB dynamic LDS; activation tile lives in
//   LDS (64KB, swizzled, sub-slab-outer); weight slabs double-buffered via
//   global_load_lds with counted vmcnt(8); final Wf-dot + sigmoid in-kernel.
//   Saves ~205MB of traffic + 3 launches. GIN layers / agg / CSR unchanged.
// (3rd resubmission: R10/R11/R12 benches all died on the same dead container
//  before compile — no signal yet on this kernel.)
// ---------------------------------------------------------------------------

#define NN  100000
#define EE  1600000
#define CIN 64
#define CC  128
#define NBK 782              // ceil(NN / 128) buckets, bucket = dst >> 7
#define CHUNK 8192           // edges per multi-split block
#define NCH 196              // ceil(EE / CHUNK)

typedef __attribute__((ext_vector_type(8))) __bf16 bf16x8;
typedef __attribute__((ext_vector_type(4))) float  f32x4;

__device__ __forceinline__ float bf2f(uint32_t u) { return __uint_as_float(u << 16); }
__device__ __forceinline__ float bf2f_hi(uint32_t u) { return __uint_as_float(u & 0xffff0000u); }
__device__ __forceinline__ ushort f2bf(float f) {          // RNE f32 -> bf16
  uint32_t u = __float_as_uint(f);
  u += 0x7fffu + ((u >> 16) & 1u);
  return (ushort)(u >> 16);
}

template<int ACT> __device__ __forceinline__ float actf(float z) {
  if constexpr (ACT == 1) return z >= 0.f ? z : 0.01f * z;       // lrelu
  else if constexpr (ACT == 2) return z >= 0.f ? z : 1e-4f * z;  // lrelu(lrelu)
  else return z;
}

// async global->LDS, 16B per lane; lds base must be wave-uniform
__device__ __forceinline__ void gload_lds16(const void* g, void* l) {
  __builtin_amdgcn_global_load_lds(
      (const __attribute__((address_space(1))) void*)g,
      (__attribute__((address_space(3))) void*)l, 16, 0, 0);
}

// ---------------- multi-split CSR build ----------------
__global__ __launch_bounds__(256) void ms_hist_kernel(const int* __restrict__ ei,
                                                      int* __restrict__ hist,
                                                      int* __restrict__ bh, int e) {
  __shared__ int h[NBK];
  for (int i = threadIdx.x; i < NBK; i += 256) h[i] = 0;
  __syncthreads();
  const int base = blockIdx.x * CHUNK;
  const int end = min(base + CHUNK, e);
  for (int i = base + threadIdx.x; i < end; i += 256)
    atomicAdd(&h[ei[e + i] >> 7], 1);
  __syncthreads();
  for (int i = threadIdx.x; i < NBK; i += 256) {
    hist[blockIdx.x * NBK + i] = h[i];
    if (h[i]) atomicAdd(&bh[i], h[i]);
  }
}

__global__ __launch_bounds__(256) void bkt_scan_kernel(const int* __restrict__ bh,
                                                       int* __restrict__ boff, int e) {
  __shared__ int sd[256];
  int t = threadIdx.x;
  int base = t * 4;
  int v0 = base + 0 < NBK ? bh[base + 0] : 0;
  int v1 = base + 1 < NBK ? bh[base + 1] : 0;
  int v2 = base + 2 < NBK ? bh[base + 2] : 0;
  int v3 = base + 3 < NBK ? bh[base + 3] : 0;
  int ts = v0 + v1 + v2 + v3;
  sd[t] = ts; __syncthreads();
  for (int off = 1; off < 256; off <<= 1) {
    int u = (t >= off) ? sd[t - off] : 0;
    __syncthreads();
    sd[t] += u;
    __syncthreads();
  }
  int excl = sd[t] - ts;
  if (base + 0 < NBK) boff[base + 0] = excl;
  if (base + 1 < NBK) boff[base + 1] = excl + v0;
  if (base + 2 < NBK) boff[base + 2] = excl + v0 + v1;
  if (base + 3 < NBK) boff[base + 3] = excl + v0 + v1 + v2;
  if (t == 255) boff[NBK] = e;
}

__global__ void ms_offs_kernel(int* __restrict__ hist, const int* __restrict__ boff) {
  int b = blockIdx.x * 256 + threadIdx.x;
  if (b >= NBK) return;
  int run = boff[b];
  for (int k = 0; k < NCH; ++k) {
    int t = hist[k * NBK + b];     // coalesced across b
    hist[k * NBK + b] = run;
    run += t;
  }
}

__global__ __launch_bounds__(256) void ms_scatter_kernel(const int* __restrict__ ei,
                                                         const int* __restrict__ hist,
                                                         uint* __restrict__ ebkt, int e) {
  __shared__ int cur[NBK];
  for (int i = threadIdx.x; i < NBK; i += 256) cur[i] = hist[blockIdx.x * NBK + i];
  __syncthreads();
  const int base = blockIdx.x * CHUNK;
  const int end = min(base + CHUNK, e);
  for (int i = base + threadIdx.x; i < end; i += 256) {
    int s = ei[i], d = ei[e + i];
    int p = atomicAdd(&cur[d >> 7], 1);
    ebkt[p] = ((uint)(d & 127) << 17) | (uint)s;
  }
}

__global__ __launch_bounds__(256) void bkt_deg_kernel(const uint* __restrict__ ebkt,
                                                      const int* __restrict__ boff,
                                                      int* __restrict__ deg, int n) {
  __shared__ int dl[128];
  int b = blockIdx.x;
  for (int i = threadIdx.x; i < 128; i += 256) dl[i] = 0;
  __syncthreads();
  int j1 = boff[b + 1];
  for (int j = boff[b] + threadIdx.x; j < j1; j += 256)
    atomicAdd(&dl[ebkt[j] >> 17], 1);
  __syncthreads();
  for (int i = threadIdx.x; i < 128; i += 256) {
    int node = (b << 7) + i;
    if (node < n) deg[node] = dl[i];
  }
}

__global__ __launch_bounds__(256) void bkt_fill_kernel(const uint* __restrict__ ebkt,
                                                       const int* __restrict__ boff,
                                                       const int* __restrict__ rowp,
                                                       int* __restrict__ colb, int n) {
  __shared__ int cur[128];
  int b = blockIdx.x;
  for (int i = threadIdx.x; i < 128; i += 256) {
    int node = (b << 7) + i;
    cur[i] = (node < n) ? rowp[node] : 0;
  }
  __syncthreads();
  int j1 = boff[b + 1];
  for (int j = boff[b] + threadIdx.x; j < j1; j += 256) {
    uint v = ebkt[j];
    int p = atomicAdd(&cur[v >> 17], 1);
    colb[p] = (int)(v & 0x1FFFFu);
  }
}

// ---------------- node-degree scan (rowp) ----------------
__global__ void scan1_kernel(const int* __restrict__ deg, int* __restrict__ outp,
                             int* __restrict__ partial, int n) {
  __shared__ int sd[256];
  int t = threadIdx.x;
  int base = blockIdx.x * 1024 + t * 4;
  int v0 = base + 0 < n ? deg[base + 0] : 0;
  int v1 = base + 1 < n ? deg[base + 1] : 0;
  int v2 = base + 2 < n ? deg[base + 2] : 0;
  int v3 = base + 3 < n ? deg[base + 3] : 0;
  int ts = v0 + v1 + v2 + v3;
  sd[t] = ts; __syncthreads();
  for (int off = 1; off < 256; off <<= 1) {
    int u = (t >= off) ? sd[t - off] : 0;
    __syncthreads();
    sd[t] += u;
    __syncthreads();
  }
  int excl = sd[t] - ts;
  if (base + 0 < n) outp[base + 0] = excl;
  if (base + 1 < n) outp[base + 1] = excl + v0;
  if (base + 2 < n) outp[base + 2] = excl + v0 + v1;
  if (base + 3 < n) outp[base + 3] = excl + v0 + v1 + v2;
  if (t == 255) partial[blockIdx.x] = sd[255];
}

__global__ void scan2_kernel(int* __restrict__ partial, int nb) {
  __shared__ int sd[256];
  int t = threadIdx.x;
  int v = t < nb ? partial[t] : 0;
  sd[t] = v; __syncthreads();
  for (int off = 1; off < 256; off <<= 1) {
    int u = (t >= off) ? sd[t - off] : 0;
    __syncthreads();
    sd[t] += u;
    __syncthreads();
  }
  if (t < nb) partial[t] = sd[t] - v;  // exclusive block offsets
}

__global__ void scan3_kernel(int* __restrict__ rowp, const int* __restrict__ partial,
                             int n, int e) {
  int i = blockIdx.x * 256 + threadIdx.x;
  if (i == 0) rowp[n] = e;
  if (i < n) rowp[i] += partial[i >> 10];
}

// ---------------- prep ----------------
__global__ void bnprep_kernel(const float* b1, const float* g1, const float* be1,
                              const float* m1, const float* v1,
                              const float* bL, const float* gL, const float* beL,
                              const float* mL, const float* vL,
                              float* __restrict__ sc, float* __restrict__ tc) {
  int i = blockIdx.x * 256 + threadIdx.x;
  if (i >= 4 * 128) return;
  int layer = i >> 7, c = i & 127;
  float b, g, be, m, v;
  if (layer == 0) { b = b1[c]; g = g1[c]; be = be1[c]; m = m1[c]; v = v1[c]; }
  else { int o = (layer - 1) * 128 + c; b = bL[o]; g = gL[o]; be = beL[o]; m = mL[o]; v = vL[o]; }
  float s = g * rsqrtf(v + 1e-5f);
  sc[i] = s;
  tc[i] = (b - m) * s + be;
}

// transpose fp32 weights -> bf16 Wt (M x K row-major)
__global__ void wtprep_kernel(const float* __restrict__ W1, const float* __restrict__ WL,
                              const float* __restrict__ Wc1, const float* __restrict__ Wcl,
                              ushort* __restrict__ wt1, ushort* __restrict__ wtL,
                              ushort* __restrict__ wtc1, ushort* __restrict__ wtcl) {
  int i = blockIdx.x * 256 + threadIdx.x;
  if (i < 8192) {                                      // W1: 64x128 -> 128x64
    int m = i >> 6, k = i & 63;
    wt1[i] = f2bf(W1[k * 128 + m]);
  } else if (i < 8192 + 49152) {                       // WL: 3 x 128x128
    int j = i - 8192;
    int l = j >> 14, r = j & 16383, m = r >> 7, k = r & 127;
    wtL[j] = f2bf(WL[l * 16384 + k * 128 + m]);
  } else if (i < 8192 + 49152 + 32768) {               // Wc1: 128x256 -> 256x128
    int j = i - (8192 + 49152);
    int m = j >> 7, k = j & 127;
    wtc1[j] = f2bf(Wc1[k * 256 + m]);
  } else if (i < 8192 + 49152 + 32768 + 131072) {      // Wcl: 2 x 256x256
    int j = i - (8192 + 49152 + 32768);
    int l = j >> 16, r = j & 65535, m = r >> 8, k = r & 255;
    wtcl[j] = f2bf(Wcl[l * 65536 + k * 256 + m]);
  }
}

// x fp32 [N][64] -> bf16 flat [N][64]
__global__ void xconv_kernel(const float* __restrict__ x, ushort* __restrict__ xb, int n4) {
  int i = blockIdx.x * 256 + threadIdx.x;
  if (i < n4) {
    float4 v = ((const float4*)x)[i];
    ushort4 o;
    o.x = f2bf(v.x); o.y = f2bf(v.y); o.z = f2bf(v.z); o.w = f2bf(v.w);
    ((ushort4*)xb)[i] = o;
  }
}

// ---------------- aggregation (flat wide-gather): zin = (1+eps)*h + sum ------
template<int C>
__global__ __launch_bounds__(256) void agg_kernel(
    const ushort* __restrict__ hb, const int* __restrict__ rowp,
    const int* __restrict__ colb, const float* __restrict__ ep,
    ushort* __restrict__ zout, int n)
{
  constexpr int LPE = C / 8;     // lanes per edge (16 for C=128, 8 for C=64)
  constexpr int EPR = 64 / LPE;  // edges per round (4 or 8)
  const int lane = threadIdx.x & 63;
  const int node = blockIdx.x * 4 + (threadIdx.x >> 6);
  if (node >= n) return;
  const float e1 = 1.0f + ep[0];
  const int lo = lane & (LPE - 1);
  const int g  = lane / LPE;
  int j0 = rowp[node], jend = rowp[node + 1];

  float a0 = 0.f, a1 = 0.f, a2 = 0.f, a3 = 0.f,
        a4 = 0.f, a5 = 0.f, a6 = 0.f, a7 = 0.f;

  for (; j0 < jend; j0 += 64) {
    int cnt = jend - j0; if (cnt > 64) cnt = 64;
    int myn = (lane < cnt) ? colb[j0 + lane] : 0;
    int rounds = (cnt + EPR - 1) / EPR;
    #pragma unroll 4
    for (int r = 0; r < rounds; ++r) {
      int e = r * EPR + g;
      int u = __shfl(myn, e);          // all lanes active for the shuffle
      if (e < cnt) {
        const uint4 v = *(const uint4*)(hb + (size_t)u * C + lo * 8);
        a0 += bf2f(v.x); a1 += bf2f_hi(v.x);
        a2 += bf2f(v.y); a3 += bf2f_hi(v.y);
        a4 += bf2f(v.z); a5 += bf2f_hi(v.z);
        a6 += bf2f(v.w); a7 += bf2f_hi(v.w);
      }
    }
  }

  // combine group partials
  #pragma unroll
  for (int s = LPE; s < 64; s <<= 1) {
    a0 += __shfl_xor(a0, s); a1 += __shfl_xor(a1, s);
    a2 += __shfl_xor(a2, s); a3 += __shfl_xor(a3, s);
    a4 += __shfl_xor(a4, s); a5 += __shfl_xor(a5, s);
    a6 += __shfl_xor(a6, s); a7 += __shfl_xor(a7, s);
  }

  if (g == 0) {
    const uint4 d = *(const uint4*)(hb + (size_t)node * C + lo * 8);
    uint4 o;
    o.x = (uint)f2bf(e1 * bf2f(d.x) + a0) | ((uint)f2bf(e1 * bf2f_hi(d.x) + a1) << 16);
    o.y = (uint)f2bf(e1 * bf2f(d.y) + a2) | ((uint)f2bf(e1 * bf2f_hi(d.y) + a3) << 16);
    o.z = (uint)f2bf(e1 * bf2f(d.z) + a4) | ((uint)f2bf(e1 * bf2f_hi(d.z) + a5) << 16);
    o.w = (uint)f2bf(e1 * bf2f(d.w) + a6) | ((uint)f2bf(e1 * bf2f_hi(d.w) + a7) << 16);
    *(uint4*)(zout + (size_t)node * C + lo * 8) = o;
  }
}

// ---------------- GEMM v4 (GIN layers): global_load_lds staging --------------
template<int K, int M, int ACT, bool BN>
__global__ __launch_bounds__(256) void gemm_kernel(
    const ushort* __restrict__ xin,   // N x K  bf16
    const ushort* __restrict__ wt,    // M x K  bf16 (row-major)
    const float*  __restrict__ sc,
    const float*  __restrict__ tc,
    ushort* __restrict__ hout,        // N x M  bf16
    int n)
{
  constexpr int KS = 64;
  __shared__ ushort ldsW[128 * KS];   // 16 KiB
  __shared__ ushort ldsX[128 * KS];   // 16 KiB
  const int tid = threadIdx.x;
  const int wave = tid >> 6, lane = tid & 63;
  const int lr = lane & 15, lg = lane >> 4;
  const int n0 = blockIdx.x * 128;
  const int mB = blockIdx.y * 128;

  f32x4 acc[8][2];
  #pragma unroll
  for (int r = 0; r < 8; ++r) {
    acc[r][0] = (f32x4){0.f, 0.f, 0.f, 0.f};
    acc[r][1] = (f32x4){0.f, 0.f, 0.f, 0.f};
  }

  #pragma unroll
  for (int s = 0; s < K / KS; ++s) {
    if (s) __syncthreads();           // previous reads done before overwrite
    #pragma unroll
    for (int i = 0; i < 4; ++i) {
      const int ub = wave * 4096 + i * 1024;       // wave-uniform lds byte base
      const int a  = ub + lane * 16;               // this lane's lds byte
      const int m  = a >> 7;                       // row (128B rows)
      const int o  = (a & 127) ^ ((m & 7) << 4);   // pre-swizzled src offset
      gload_lds16((const char*)wt + ((size_t)(mB + m) * K) * 2 + s * 128 + o,
                  (char*)ldsW + ub);
      int nd = n0 + m; if (nd >= n) nd = n - 1;
      gload_lds16((const char*)xin + ((size_t)nd * K) * 2 + s * 128 + o,
                  (char*)ldsX + ub);
    }
    asm volatile("s_waitcnt vmcnt(0)" ::: "memory");
    __syncthreads();
    #pragma unroll
    for (int k0 = 0; k0 < KS; k0 += 32) {
      const int kb = (k0 + lg * 8) * 2;  // byte offset of this lane's 16B in a row
      bf16x8 wf0, wf1;
      {
        int m = wave * 32 + lr;
        wf0 = __builtin_bit_cast(bf16x8,
              *(const uint4*)((const char*)ldsW + ((m * 128 + kb) ^ ((m & 7) << 4))));
        m += 16;
        wf1 = __builtin_bit_cast(bf16x8,
              *(const uint4*)((const char*)ldsW + ((m * 128 + kb) ^ ((m & 7) << 4))));
      }
      #pragma unroll
      for (int r = 0; r < 8; ++r) {
        int xr = r * 16 + lr;
        bf16x8 xf = __builtin_bit_cast(bf16x8,
              *(const uint4*)((const char*)ldsX + ((xr * 128 + kb) ^ ((xr & 7) << 4))));
        acc[r][0] = __builtin_amdgcn_mfma_f32_16x16x32_bf16(wf0, xf, acc[r][0], 0, 0, 0);
        acc[r][1] = __builtin_amdgcn_mfma_f32_16x16x32_bf16(wf1, xf, acc[r][1], 0, 0, 0);
      }
    }
  }

  #pragma unroll
  for (int ct = 0; ct < 2; ++ct) {
    const int c0 = mB + wave * 32 + ct * 16 + lg * 4;
    float4 sv;
    if constexpr (BN) sv = *(const float4*)(sc + c0);
    else sv = make_float4(1.f, 1.f, 1.f, 1.f);
    const float4 tv = *(const float4*)(tc + c0);
    #pragma unroll
    for (int r = 0; r < 8; ++r) {
      const int node = n0 + r * 16 + lr;
      if (node < n) {
        const f32x4 a = acc[r][ct];
        ushort4 o;
        o.x = f2bf(actf<ACT>(a[0] * sv.x + tv.x));
        o.y = f2bf(actf<ACT>(a[1] * sv.y + tv.y));
        o.z = f2bf(actf<ACT>(a[2] * sv.z + tv.z));
        o.w = f2bf(actf<ACT>(a[3] * sv.w + tv.w));
        *(ushort4*)(hout + (size_t)node * M + c0) = o;
      }
    }
  }
}

// ---------------- fused classifier: c1 + c2 + c3 + Wf-dot + sigmoid ----------
// block = 128 nodes. Dynamic LDS 144KB:
//   ldsW0[32KB] | ldsW1[32KB] | ldsH[64KB: 4 subslabs x 128 nodes x 64ch] | ldsX[16KB]
__global__ __launch_bounds__(256) void cls_kernel(
    const ushort* __restrict__ xin,   // N x 128 bf16 (GIN output)
    const ushort* __restrict__ wc1,   // 256 x 128 bf16
    const float*  __restrict__ bc1,   // 256
    const ushort* __restrict__ wcl,   // 2 x 256 x 256 bf16
    const float*  __restrict__ bcl,   // 2 x 256
    const float*  __restrict__ wfv,   // 256
    const float*  __restrict__ bfp,   // 1
    float* __restrict__ out, int n)
{
  extern __shared__ char lds[];
  char* ldsW0 = lds;
  char* ldsW1 = lds + 32768;
  char* ldsH  = lds + 65536;
  char* ldsX  = lds + 131072;
  const int tid = threadIdx.x;
  const int wave = tid >> 6, lane = tid & 63;
  const int lr = lane & 15, lg = lane >> 4;
  const int n0 = blockIdx.x * 128;

  f32x4 acc[8][4];

  // stage a 256-row x 64-ch W slab (32KB); wave covers 8KB
  auto stageW = [&](const ushort* wsrc, int K2, int s, char* dst) {
    #pragma unroll
    for (int i = 0; i < 8; ++i) {
      const int ub = wave * 8192 + i * 1024;
      const int a = ub + lane * 16;
      const int m = a >> 7;
      const int o = (a & 127) ^ ((m & 7) << 4);
      gload_lds16((const char*)wsrc + (size_t)m * K2 * 2 + s * 128 + o, dst + ub);
    }
  };
  // stage 128-node x 64-ch X slab (16KB); wave covers 4KB
  auto stageX = [&](int s) {
    #pragma unroll
    for (int i = 0; i < 4; ++i) {
      const int ub = wave * 4096 + i * 1024;
      const int a = ub + lane * 16;
      const int m = a >> 7;
      const int o = (a & 127) ^ ((m & 7) << 4);
      int nd = n0 + m; if (nd >= n) nd = n - 1;
      gload_lds16((const char*)xin + (size_t)nd * 128 * 2 + s * 128 + o, ldsX + ub);
    }
  };
  // one K=64 slab of MFMAs: W rows wave*64+ct*16+lr, X rows rowOff+r*16+lr
  auto mfma_slab = [&](const char* wbuf, const char* xbase, int rowOff) {
    #pragma unroll
    for (int k0 = 0; k0 < 64; k0 += 32) {
      const int kb = (k0 + lg * 8) * 2;
      bf16x8 wfr[4];
      #pragma unroll
      for (int ct = 0; ct < 4; ++ct) {
        int m = wave * 64 + ct * 16 + lr;
        wfr[ct] = __builtin_bit_cast(bf16x8,
                  *(const uint4*)(wbuf + ((m * 128 + kb) ^ ((m & 7) << 4))));
      }
      #pragma unroll
      for (int r = 0; r < 8; ++r) {
        int xr = rowOff + r * 16 + lr;
        bf16x8 xf = __builtin_bit_cast(bf16x8,
                    *(const uint4*)(xbase + ((xr * 128 + kb) ^ ((xr & 7) << 4))));
        #pragma unroll
        for (int ct = 0; ct < 4; ++ct)
          acc[r][ct] = __builtin_amdgcn_mfma_f32_16x16x32_bf16(wfr[ct], xf, acc[r][ct], 0, 0, 0);
      }
    }
  };
  auto zacc = [&]() {
    #pragma unroll
    for (int r = 0; r < 8; ++r)
      #pragma unroll
      for (int c = 0; c < 4; ++c) acc[r][c] = (f32x4){0.f, 0.f, 0.f, 0.f};
  };

  // ---- c1: h1 = X(128) @ Wc1^T + bc1 ----
  zacc();
  #pragma unroll
  for (int s = 0; s < 2; ++s) {
    if (s) __syncthreads();
    stageX(s);
    stageW(wc1, 128, s, ldsW0);
    asm volatile("s_waitcnt vmcnt(0)" ::: "memory");
    __syncthreads();
    mfma_slab(ldsW0, ldsX, 0);
  }
  __syncthreads();
  // h1 (+bc1, no act) -> ldsH
  #pragma unroll
  for (int ct = 0; ct < 4; ++ct) {
    const int c0 = wave * 64 + ct * 16 + lg * 4;
    const float4 bv = *(const float4*)(bc1 + c0);
    #pragma unroll
    for (int r = 0; r < 8; ++r) {
      const int nl = r * 16 + lr;
      const int rowH = wave * 128 + nl;        // subslab = wave
      const f32x4 a = acc[r][ct];
      ushort4 o;
      o.x = f2bf(a[0] + bv.x); o.y = f2bf(a[1] + bv.y);
      o.z = f2bf(a[2] + bv.z); o.w = f2bf(a[3] + bv.w);
      *(ushort4*)(ldsH + ((rowH * 128 + (c0 & 63) * 2) ^ ((rowH & 7) << 4))) = o;
    }
  }

  // ---- c2 (g=0): h2 = lrelu(h1 @ Wcl0^T + bcl0) -> ldsH
  // ---- c3 (g=1): logit = lrelu(h2 @ Wcl1^T + bcl1) . Wf + bf -> sigmoid
  for (int g = 0; g < 2; ++g) {
    const ushort* Wg = wcl + g * 65536;
    const float*  bg = bcl + g * 256;
    zacc();
    __syncthreads();                            // h-writes visible; ldsW free
    stageW(Wg, 256, 0, ldsW0);
    #pragma unroll
    for (int s = 0; s < 4; ++s) {
      char* cur = (s & 1) ? ldsW1 : ldsW0;
      char* nxt = (s & 1) ? ldsW0 : ldsW1;
      if (s + 1 < 4) {
        stageW(Wg, 256, s + 1, nxt);
        asm volatile("s_waitcnt vmcnt(8)" ::: "memory");
      } else {
        asm volatile("s_waitcnt vmcnt(0)" ::: "memory");
      }
      __syncthreads();
      mfma_slab(cur, ldsH, s * 128);
      __syncthreads();
    }
    if (g == 0) {
      #pragma unroll
      for (int ct = 0; ct < 4; ++ct) {
        const int c0 = wave * 64 + ct * 16 + lg * 4;
        const float4 bv = *(const float4*)(bg + c0);
        #pragma unroll
        for (int r = 0; r < 8; ++r) {
          const int nl = r * 16 + lr;
          const int rowH = wave * 128 + nl;
          const f32x4 a = acc[r][ct];
          ushort4 o;
          o.x = f2bf(actf<1>(a[0] + bv.x)); o.y = f2bf(actf<1>(a[1] + bv.y));
          o.z = f2bf(actf<1>(a[2] + bv.z)); o.w = f2bf(actf<1>(a[3] + bv.w));
          *(ushort4*)(ldsH + ((rowH * 128 + (c0 & 63) * 2) ^ ((rowH & 7) << 4))) = o;
        }
      }
    } else {
      float* red = (float*)ldsX;
      #pragma unroll
      for (int r = 0; r < 8; ++r) {
        float p = 0.f;
        #pragma unroll
        for (int ct = 0; ct < 4; ++ct) {
          const int c0 = wave * 64 + ct * 16 + lg * 4;
          const float4 bv = *(const float4*)(bg + c0);
          const float4 wv = *(const float4*)(wfv + c0);
          const f32x4 a = acc[r][ct];
          p += actf<1>(a[0] + bv.x) * wv.x + actf<1>(a[1] + bv.y) * wv.y
             + actf<1>(a[2] + bv.z) * wv.z + actf<1>(a[3] + bv.w) * wv.w;
        }
        p += __shfl_xor(p, 16);
        p += __shfl_xor(p, 32);
        if (lg == 0) red[wave * 128 + r * 16 + lr] = p;
      }
      __syncthreads();
      if (tid < 128) {
        const int nd = n0 + tid;
        if (nd < n) {
          float logit = red[tid] + red[128 + tid] + red[256 + tid] + red[384 + tid] + bfp[0];
          out[nd] = 1.f / (1.f + expf(-logit));
        }
      }
    }
  }
}

// ---------------- launch ----------------
extern "C" void kernel_launch(void* const* d_in, const int* in_sizes, int n_in,
                              void* d_out, int out_size, void* d_ws, size_t ws_size,
                              hipStream_t stream)
{
  const float* x    = (const float*)d_in[0];
  const int*   ei   = (const int*)d_in[1];
  const float* eps1 = (const float*)d_in[3];
  const float* W1   = (const float*)d_in[4];
  const float* b1   = (const float*)d_in[5];
  const float* g1   = (const float*)d_in[6];
  const float* be1  = (const float*)d_in[7];
  const float* m1   = (const float*)d_in[8];
  const float* v1   = (const float*)d_in[9];
  const float* epsL = (const float*)d_in[10];
  const float* WL   = (const float*)d_in[11];
  const float* bL   = (const float*)d_in[12];
  const float* gL   = (const float*)d_in[13];
  const float* beL  = (const float*)d_in[14];
  const float* mL   = (const float*)d_in[15];
  const float* vL   = (const float*)d_in[16];
  const float* Wc1  = (const float*)d_in[17];
  const float* bc1  = (const float*)d_in[18];
  const float* Wcl  = (const float*)d_in[19];
  const float* bcl  = (const float*)d_in[20];
  const float* Wf   = (const float*)d_in[21];
  const float* bfp  = (const float*)d_in[22];
  float* out = (float*)d_out;

  char* w = (char*)d_ws;
  size_t off = 0;
  auto alloc = [&](size_t bytes) {
    char* p = w + off;
    off += (bytes + 255) & ~(size_t)255;
    return p;
  };
  ushort* bufA   = (ushort*)alloc((size_t)NN * 256 * 2);   // 51.2 MB
  ushort* bufB   = (ushort*)alloc((size_t)NN * 256 * 2);   // 51.2 MB
  int*    rowp   = (int*)alloc((NN + 1) * 4);
  int*    deg    = (int*)alloc(NN * 4);
  int*    colb   = (int*)alloc((size_t)EE * 4);
  uint*   ebkt   = (uint*)alloc((size_t)EE * 4);
  int*    hist   = (int*)alloc((size_t)NCH * NBK * 4);     // 613 KB
  int*    bh     = (int*)alloc(NBK * 4);
  int*    boff   = (int*)alloc((NBK + 1) * 4);
  int*    partial= (int*)alloc(1024);
  ushort* wt1    = (ushort*)alloc(8192 * 2);
  ushort* wtL    = (ushort*)alloc(49152 * 2);
  ushort* wtc1   = (ushort*)alloc(32768 * 2);
  ushort* wtcl   = (ushort*)alloc(131072 * 2);
  float*  sc     = (float*)alloc(512 * 4);
  float*  tc     = (float*)alloc(512 * 4);
  (void)ws_size; (void)in_sizes; (void)n_in; (void)out_size;

  // multi-split CSR build (by dst), no global atomics in the scatter
  hipMemsetAsync(bh, 0, NBK * 4, stream);
  ms_hist_kernel<<<NCH, 256, 0, stream>>>(ei, hist, bh, EE);
  bkt_scan_kernel<<<1, 256, 0, stream>>>(bh, boff, EE);
  ms_offs_kernel<<<(NBK + 255) / 256, 256, 0, stream>>>(hist, boff);
  ms_scatter_kernel<<<NCH, 256, 0, stream>>>(ei, hist, ebkt, EE);
  bkt_deg_kernel<<<NBK, 256, 0, stream>>>(ebkt, boff, deg, NN);
  scan1_kernel<<<98, 256, 0, stream>>>(deg, rowp, partial, NN);
  scan2_kernel<<<1, 256, 0, stream>>>(partial, 98);
  scan3_kernel<<<(NN + 255) / 256, 256, 0, stream>>>(rowp, partial, NN, EE);
  bkt_fill_kernel<<<NBK, 256, 0, stream>>>(ebkt, boff, rowp, colb, NN);

  // prep
  bnprep_kernel<<<2, 256, 0, stream>>>(b1, g1, be1, m1, v1, bL, gL, beL, mL, vL, sc, tc);
  wtprep_kernel<<<864, 256, 0, stream>>>(W1, WL, Wc1, Wcl, wt1, wtL, wtc1, wtcl);
  xconv_kernel<<<(NN * CIN / 4 + 255) / 256, 256, 0, stream>>>(x, bufA, NN * CIN / 4);

  const int GB = (NN + 127) / 128;   // 782 node-tiles

  // GIN layer 1 (64 -> 128), double lrelu
  agg_kernel<64><<<25000, 256, 0, stream>>>(bufA, rowp, colb, eps1, bufB, NN);
  gemm_kernel<64, 128, 2, true><<<dim3(GB, 1), 256, 0, stream>>>(bufB, wt1, sc, tc, bufA, NN);
  // GIN layers 2-4 (128 -> 128), double lrelu
  for (int i = 0; i < 3; ++i) {
    agg_kernel<128><<<25000, 256, 0, stream>>>(bufA, rowp, colb, epsL + i, bufB, NN);
    gemm_kernel<128, 128, 2, true><<<dim3(GB, 1), 256, 0, stream>>>(
        bufB, wtL + i * 16384, sc + 128 * (i + 1), tc + 128 * (i + 1), bufA, NN);
  }
  // fused classifier + final (reads bufA, writes out)
  hipFuncSetAttribute(reinterpret_cast<const void*>(cls_kernel),
                      hipFuncAttributeMaxDynamicSharedMemorySize, 147456);
  cls_kernel<<<GB, 256, 147456, stream>>>(bufA, wtc1, bc1, wtcl, bcl, Wf, bfp, out, NN);
}

// Round 16
// 455.008 us; speedup vs baseline: 2.4500x; 1.0470x over previous
//
#include <hip/hip_runtime.h>
#include <stdint.h>

// ---------------------------------------------------------------------------
// GIN (4 layers, CSR gather aggregation) + MLP classifier, bf16 MFMA GEMMs.
// R14-R16 change: cls_kernel widened to 512 threads (8 waves = 2 waves/SIMD).
//   R13's fused classifier worked traffic-wise (FETCH 150->14MB) but ran 93us:
//   144KB LDS -> 1 block/CU -> 1 wave/SIMD -> every stage/barrier latency
//   exposed (MfmaUtil 13%). Now 8 waves share the same tile (32 out-ch/wave,
//   acc[8][2]); 2 waves/SIMD co-schedule, staging spread over 8 waves,
//   W dbuf waits use counted vmcnt(4). LDS layout/footprint unchanged.
// (2nd resubmission: R14/R15 benches died on the known-dead container before
//  compile; R13 proved retries can land on live hardware.)
// ---------------------------------------------------------------------------

#define NN  100000
#define EE  1600000
#define CIN 64
#define CC  128
#define NBK 782              // ceil(NN / 128) buckets, bucket = dst >> 7
#define CHUNK 8192           // edges per multi-split block
#define NCH 196              // ceil(EE / CHUNK)

typedef __attribute__((ext_vector_type(8))) __bf16 bf16x8;
typedef __attribute__((ext_vector_type(4))) float  f32x4;

__device__ __forceinline__ float bf2f(uint32_t u) { return __uint_as_float(u << 16); }
__device__ __forceinline__ float bf2f_hi(uint32_t u) { return __uint_as_float(u & 0xffff0000u); }
__device__ __forceinline__ ushort f2bf(float f) {          // RNE f32 -> bf16
  uint32_t u = __float_as_uint(f);
  u += 0x7fffu + ((u >> 16) & 1u);
  return (ushort)(u >> 16);
}

template<int ACT> __device__ __forceinline__ float actf(float z) {
  if constexpr (ACT == 1) return z >= 0.f ? z : 0.01f * z;       // lrelu
  else if constexpr (ACT == 2) return z >= 0.f ? z : 1e-4f * z;  // lrelu(lrelu)
  else return z;
}

// async global->LDS, 16B per lane; lds base must be wave-uniform
__device__ __forceinline__ void gload_lds16(const void* g, void* l) {
  __builtin_amdgcn_global_load_lds(
      (const __attribute__((address_space(1))) void*)g,
      (__attribute__((address_space(3))) void*)l, 16, 0, 0);
}

// ---------------- multi-split CSR build ----------------
__global__ __launch_bounds__(256) void ms_hist_kernel(const int* __restrict__ ei,
                                                      int* __restrict__ hist,
                                                      int* __restrict__ bh, int e) {
  __shared__ int h[NBK];
  for (int i = threadIdx.x; i < NBK; i += 256) h[i] = 0;
  __syncthreads();
  const int base = blockIdx.x * CHUNK;
  const int end = min(base + CHUNK, e);
  for (int i = base + threadIdx.x; i < end; i += 256)
    atomicAdd(&h[ei[e + i] >> 7], 1);
  __syncthreads();
  for (int i = threadIdx.x; i < NBK; i += 256) {
    hist[blockIdx.x * NBK + i] = h[i];
    if (h[i]) atomicAdd(&bh[i], h[i]);
  }
}

__global__ __launch_bounds__(256) void bkt_scan_kernel(const int* __restrict__ bh,
                                                       int* __restrict__ boff, int e) {
  __shared__ int sd[256];
  int t = threadIdx.x;
  int base = t * 4;
  int v0 = base + 0 < NBK ? bh[base + 0] : 0;
  int v1 = base + 1 < NBK ? bh[base + 1] : 0;
  int v2 = base + 2 < NBK ? bh[base + 2] : 0;
  int v3 = base + 3 < NBK ? bh[base + 3] : 0;
  int ts = v0 + v1 + v2 + v3;
  sd[t] = ts; __syncthreads();
  for (int off = 1; off < 256; off <<= 1) {
    int u = (t >= off) ? sd[t - off] : 0;
    __syncthreads();
    sd[t] += u;
    __syncthreads();
  }
  int excl = sd[t] - ts;
  if (base + 0 < NBK) boff[base + 0] = excl;
  if (base + 1 < NBK) boff[base + 1] = excl + v0;
  if (base + 2 < NBK) boff[base + 2] = excl + v0 + v1;
  if (base + 3 < NBK) boff[base + 3] = excl + v0 + v1 + v2;
  if (t == 255) boff[NBK] = e;
}

__global__ void ms_offs_kernel(int* __restrict__ hist, const int* __restrict__ boff) {
  int b = blockIdx.x * 256 + threadIdx.x;
  if (b >= NBK) return;
  int run = boff[b];
  for (int k = 0; k < NCH; ++k) {
    int t = hist[k * NBK + b];     // coalesced across b
    hist[k * NBK + b] = run;
    run += t;
  }
}

__global__ __launch_bounds__(256) void ms_scatter_kernel(const int* __restrict__ ei,
                                                         const int* __restrict__ hist,
                                                         uint* __restrict__ ebkt, int e) {
  __shared__ int cur[NBK];
  for (int i = threadIdx.x; i < NBK; i += 256) cur[i] = hist[blockIdx.x * NBK + i];
  __syncthreads();
  const int base = blockIdx.x * CHUNK;
  const int end = min(base + CHUNK, e);
  for (int i = base + threadIdx.x; i < end; i += 256) {
    int s = ei[i], d = ei[e + i];
    int p = atomicAdd(&cur[d >> 7], 1);
    ebkt[p] = ((uint)(d & 127) << 17) | (uint)s;
  }
}

__global__ __launch_bounds__(256) void bkt_deg_kernel(const uint* __restrict__ ebkt,
                                                      const int* __restrict__ boff,
                                                      int* __restrict__ deg, int n) {
  __shared__ int dl[128];
  int b = blockIdx.x;
  for (int i = threadIdx.x; i < 128; i += 256) dl[i] = 0;
  __syncthreads();
  int j1 = boff[b + 1];
  for (int j = boff[b] + threadIdx.x; j < j1; j += 256)
    atomicAdd(&dl[ebkt[j] >> 17], 1);
  __syncthreads();
  for (int i = threadIdx.x; i < 128; i += 256) {
    int node = (b << 7) + i;
    if (node < n) deg[node] = dl[i];
  }
}

__global__ __launch_bounds__(256) void bkt_fill_kernel(const uint* __restrict__ ebkt,
                                                       const int* __restrict__ boff,
                                                       const int* __restrict__ rowp,
                                                       int* __restrict__ colb, int n) {
  __shared__ int cur[128];
  int b = blockIdx.x;
  for (int i = threadIdx.x; i < 128; i += 256) {
    int node = (b << 7) + i;
    cur[i] = (node < n) ? rowp[node] : 0;
  }
  __syncthreads();
  int j1 = boff[b + 1];
  for (int j = boff[b] + threadIdx.x; j < j1; j += 256) {
    uint v = ebkt[j];
    int p = atomicAdd(&cur[v >> 17], 1);
    colb[p] = (int)(v & 0x1FFFFu);
  }
}

// ---------------- node-degree scan (rowp) ----------------
__global__ void scan1_kernel(const int* __restrict__ deg, int* __restrict__ outp,
                             int* __restrict__ partial, int n) {
  __shared__ int sd[256];
  int t = threadIdx.x;
  int base = blockIdx.x * 1024 + t * 4;
  int v0 = base + 0 < n ? deg[base + 0] : 0;
  int v1 = base + 1 < n ? deg[base + 1] : 0;
  int v2 = base + 2 < n ? deg[base + 2] : 0;
  int v3 = base + 3 < n ? deg[base + 3] : 0;
  int ts = v0 + v1 + v2 + v3;
  sd[t] = ts; __syncthreads();
  for (int off = 1; off < 256; off <<= 1) {
    int u = (t >= off) ? sd[t - off] : 0;
    __syncthreads();
    sd[t] += u;
    __syncthreads();
  }
  int excl = sd[t] - ts;
  if (base + 0 < n) outp[base + 0] = excl;
  if (base + 1 < n) outp[base + 1] = excl + v0;
  if (base + 2 < n) outp[base + 2] = excl + v0 + v1;
  if (base + 3 < n) outp[base + 3] = excl + v0 + v1 + v2;
  if (t == 255) partial[blockIdx.x] = sd[255];
}

__global__ void scan2_kernel(int* __restrict__ partial, int nb) {
  __shared__ int sd[256];
  int t = threadIdx.x;
  int v = t < nb ? partial[t] : 0;
  sd[t] = v; __syncthreads();
  for (int off = 1; off < 256; off <<= 1) {
    int u = (t >= off) ? sd[t - off] : 0;
    __syncthreads();
    sd[t] += u;
    __syncthreads();
  }
  if (t < nb) partial[t] = sd[t] - v;  // exclusive block offsets
}

__global__ void scan3_kernel(int* __restrict__ rowp, const int* __restrict__ partial,
                             int n, int e) {
  int i = blockIdx.x * 256 + threadIdx.x;
  if (i == 0) rowp[n] = e;
  if (i < n) rowp[i] += partial[i >> 10];
}

// ---------------- prep ----------------
__global__ void bnprep_kernel(const float* b1, const float* g1, const float* be1,
                              const float* m1, const float* v1,
                              const float* bL, const float* gL, const float* beL,
                              const float* mL, const float* vL,
                              float* __restrict__ sc, float* __restrict__ tc) {
  int i = blockIdx.x * 256 + threadIdx.x;
  if (i >= 4 * 128) return;
  int layer = i >> 7, c = i & 127;
  float b, g, be, m, v;
  if (layer == 0) { b = b1[c]; g = g1[c]; be = be1[c]; m = m1[c]; v = v1[c]; }
  else { int o = (layer - 1) * 128 + c; b = bL[o]; g = gL[o]; be = beL[o]; m = mL[o]; v = vL[o]; }
  float s = g * rsqrtf(v + 1e-5f);
  sc[i] = s;
  tc[i] = (b - m) * s + be;
}

// transpose fp32 weights -> bf16 Wt (M x K row-major)
__global__ void wtprep_kernel(const float* __restrict__ W1, const float* __restrict__ WL,
                              const float* __restrict__ Wc1, const float* __restrict__ Wcl,
                              ushort* __restrict__ wt1, ushort* __restrict__ wtL,
                              ushort* __restrict__ wtc1, ushort* __restrict__ wtcl) {
  int i = blockIdx.x * 256 + threadIdx.x;
  if (i < 8192) {                                      // W1: 64x128 -> 128x64
    int m = i >> 6, k = i & 63;
    wt1[i] = f2bf(W1[k * 128 + m]);
  } else if (i < 8192 + 49152) {                       // WL: 3 x 128x128
    int j = i - 8192;
    int l = j >> 14, r = j & 16383, m = r >> 7, k = r & 127;
    wtL[j] = f2bf(WL[l * 16384 + k * 128 + m]);
  } else if (i < 8192 + 49152 + 32768) {               // Wc1: 128x256 -> 256x128
    int j = i - (8192 + 49152);
    int m = j >> 7, k = j & 127;
    wtc1[j] = f2bf(Wc1[k * 256 + m]);
  } else if (i < 8192 + 49152 + 32768 + 131072) {      // Wcl: 2 x 256x256
    int j = i - (8192 + 49152 + 32768);
    int l = j >> 16, r = j & 65535, m = r >> 8, k = r & 255;
    wtcl[j] = f2bf(Wcl[l * 65536 + k * 256 + m]);
  }
}

// x fp32 [N][64] -> bf16 flat [N][64]
__global__ void xconv_kernel(const float* __restrict__ x, ushort* __restrict__ xb, int n4) {
  int i = blockIdx.x * 256 + threadIdx.x;
  if (i < n4) {
    float4 v = ((const float4*)x)[i];
    ushort4 o;
    o.x = f2bf(v.x); o.y = f2bf(v.y); o.z = f2bf(v.z); o.w = f2bf(v.w);
    ((ushort4*)xb)[i] = o;
  }
}

// ---------------- aggregation (flat wide-gather): zin = (1+eps)*h + sum ------
template<int C>
__global__ __launch_bounds__(256) void agg_kernel(
    const ushort* __restrict__ hb, const int* __restrict__ rowp,
    const int* __restrict__ colb, const float* __restrict__ ep,
    ushort* __restrict__ zout, int n)
{
  constexpr int LPE = C / 8;     // lanes per edge (16 for C=128, 8 for C=64)
  constexpr int EPR = 64 / LPE;  // edges per round (4 or 8)
  const int lane = threadIdx.x & 63;
  const int node = blockIdx.x * 4 + (threadIdx.x >> 6);
  if (node >= n) return;
  const float e1 = 1.0f + ep[0];
  const int lo = lane & (LPE - 1);
  const int g  = lane / LPE;
  int j0 = rowp[node], jend = rowp[node + 1];

  float a0 = 0.f, a1 = 0.f, a2 = 0.f, a3 = 0.f,
        a4 = 0.f, a5 = 0.f, a6 = 0.f, a7 = 0.f;

  for (; j0 < jend; j0 += 64) {
    int cnt = jend - j0; if (cnt > 64) cnt = 64;
    int myn = (lane < cnt) ? colb[j0 + lane] : 0;
    int rounds = (cnt + EPR - 1) / EPR;
    #pragma unroll 4
    for (int r = 0; r < rounds; ++r) {
      int e = r * EPR + g;
      int u = __shfl(myn, e);          // all lanes active for the shuffle
      if (e < cnt) {
        const uint4 v = *(const uint4*)(hb + (size_t)u * C + lo * 8);
        a0 += bf2f(v.x); a1 += bf2f_hi(v.x);
        a2 += bf2f(v.y); a3 += bf2f_hi(v.y);
        a4 += bf2f(v.z); a5 += bf2f_hi(v.z);
        a6 += bf2f(v.w); a7 += bf2f_hi(v.w);
      }
    }
  }

  // combine group partials
  #pragma unroll
  for (int s = LPE; s < 64; s <<= 1) {
    a0 += __shfl_xor(a0, s); a1 += __shfl_xor(a1, s);
    a2 += __shfl_xor(a2, s); a3 += __shfl_xor(a3, s);
    a4 += __shfl_xor(a4, s); a5 += __shfl_xor(a5, s);
    a6 += __shfl_xor(a6, s); a7 += __shfl_xor(a7, s);
  }

  if (g == 0) {
    const uint4 d = *(const uint4*)(hb + (size_t)node * C + lo * 8);
    uint4 o;
    o.x = (uint)f2bf(e1 * bf2f(d.x) + a0) | ((uint)f2bf(e1 * bf2f_hi(d.x) + a1) << 16);
    o.y = (uint)f2bf(e1 * bf2f(d.y) + a2) | ((uint)f2bf(e1 * bf2f_hi(d.y) + a3) << 16);
    o.z = (uint)f2bf(e1 * bf2f(d.z) + a4) | ((uint)f2bf(e1 * bf2f_hi(d.z) + a5) << 16);
    o.w = (uint)f2bf(e1 * bf2f(d.w) + a6) | ((uint)f2bf(e1 * bf2f_hi(d.w) + a7) << 16);
    *(uint4*)(zout + (size_t)node * C + lo * 8) = o;
  }
}

// ---------------- GEMM v4 (GIN layers): global_load_lds staging --------------
template<int K, int M, int ACT, bool BN>
__global__ __launch_bounds__(256) void gemm_kernel(
    const ushort* __restrict__ xin,   // N x K  bf16
    const ushort* __restrict__ wt,    // M x K  bf16 (row-major)
    const float*  __restrict__ sc,
    const float*  __restrict__ tc,
    ushort* __restrict__ hout,        // N x M  bf16
    int n)
{
  constexpr int KS = 64;
  __shared__ ushort ldsW[128 * KS];   // 16 KiB
  __shared__ ushort ldsX[128 * KS];   // 16 KiB
  const int tid = threadIdx.x;
  const int wave = tid >> 6, lane = tid & 63;
  const int lr = lane & 15, lg = lane >> 4;
  const int n0 = blockIdx.x * 128;
  const int mB = blockIdx.y * 128;

  f32x4 acc[8][2];
  #pragma unroll
  for (int r = 0; r < 8; ++r) {
    acc[r][0] = (f32x4){0.f, 0.f, 0.f, 0.f};
    acc[r][1] = (f32x4){0.f, 0.f, 0.f, 0.f};
  }

  #pragma unroll
  for (int s = 0; s < K / KS; ++s) {
    if (s) __syncthreads();           // previous reads done before overwrite
    #pragma unroll
    for (int i = 0; i < 4; ++i) {
      const int ub = wave * 4096 + i * 1024;       // wave-uniform lds byte base
      const int a  = ub + lane * 16;               // this lane's lds byte
      const int m  = a >> 7;                       // row (128B rows)
      const int o  = (a & 127) ^ ((m & 7) << 4);   // pre-swizzled src offset
      gload_lds16((const char*)wt + ((size_t)(mB + m) * K) * 2 + s * 128 + o,
                  (char*)ldsW + ub);
      int nd = n0 + m; if (nd >= n) nd = n - 1;
      gload_lds16((const char*)xin + ((size_t)nd * K) * 2 + s * 128 + o,
                  (char*)ldsX + ub);
    }
    asm volatile("s_waitcnt vmcnt(0)" ::: "memory");
    __syncthreads();
    #pragma unroll
    for (int k0 = 0; k0 < KS; k0 += 32) {
      const int kb = (k0 + lg * 8) * 2;  // byte offset of this lane's 16B in a row
      bf16x8 wf0, wf1;
      {
        int m = wave * 32 + lr;
        wf0 = __builtin_bit_cast(bf16x8,
              *(const uint4*)((const char*)ldsW + ((m * 128 + kb) ^ ((m & 7) << 4))));
        m += 16;
        wf1 = __builtin_bit_cast(bf16x8,
              *(const uint4*)((const char*)ldsW + ((m * 128 + kb) ^ ((m & 7) << 4))));
      }
      #pragma unroll
      for (int r = 0; r < 8; ++r) {
        int xr = r * 16 + lr;
        bf16x8 xf = __builtin_bit_cast(bf16x8,
              *(const uint4*)((const char*)ldsX + ((xr * 128 + kb) ^ ((xr & 7) << 4))));
        acc[r][0] = __builtin_amdgcn_mfma_f32_16x16x32_bf16(wf0, xf, acc[r][0], 0, 0, 0);
        acc[r][1] = __builtin_amdgcn_mfma_f32_16x16x32_bf16(wf1, xf, acc[r][1], 0, 0, 0);
      }
    }
  }

  #pragma unroll
  for (int ct = 0; ct < 2; ++ct) {
    const int c0 = mB + wave * 32 + ct * 16 + lg * 4;
    float4 sv;
    if constexpr (BN) sv = *(const float4*)(sc + c0);
    else sv = make_float4(1.f, 1.f, 1.f, 1.f);
    const float4 tv = *(const float4*)(tc + c0);
    #pragma unroll
    for (int r = 0; r < 8; ++r) {
      const int node = n0 + r * 16 + lr;
      if (node < n) {
        const f32x4 a = acc[r][ct];
        ushort4 o;
        o.x = f2bf(actf<ACT>(a[0] * sv.x + tv.x));
        o.y = f2bf(actf<ACT>(a[1] * sv.y + tv.y));
        o.z = f2bf(actf<ACT>(a[2] * sv.z + tv.z));
        o.w = f2bf(actf<ACT>(a[3] * sv.w + tv.w));
        *(ushort4*)(hout + (size_t)node * M + c0) = o;
      }
    }
  }
}

// ---------------- fused classifier: c1 + c2 + c3 + Wf-dot + sigmoid ----------
// block = 128 nodes, 512 threads (8 waves, 32 out-ch each). Dynamic LDS 144KB:
//   ldsW0[32KB] | ldsW1[32KB] | ldsH[64KB: 4 K-slabs x 128 nodes x 64ch] | ldsX[16KB]
__global__ __launch_bounds__(512) void cls_kernel(
    const ushort* __restrict__ xin,   // N x 128 bf16 (GIN output)
    const ushort* __restrict__ wc1,   // 256 x 128 bf16
    const float*  __restrict__ bc1,   // 256
    const ushort* __restrict__ wcl,   // 2 x 256 x 256 bf16
    const float*  __restrict__ bcl,   // 2 x 256
    const float*  __restrict__ wfv,   // 256
    const float*  __restrict__ bfp,   // 1
    float* __restrict__ out, int n)
{
  extern __shared__ char lds[];
  char* ldsW0 = lds;
  char* ldsW1 = lds + 32768;
  char* ldsH  = lds + 65536;
  char* ldsX  = lds + 131072;
  const int tid = threadIdx.x;
  const int wave = tid >> 6, lane = tid & 63;
  const int lr = lane & 15, lg = lane >> 4;
  const int n0 = blockIdx.x * 128;

  f32x4 acc[8][2];

  // stage a 256-row x 64-ch W slab (32KB); each of 8 waves covers 4KB
  auto stageW = [&](const ushort* wsrc, int K2, int s, char* dst) {
    #pragma unroll
    for (int i = 0; i < 4; ++i) {
      const int ub = wave * 4096 + i * 1024;
      const int a = ub + lane * 16;
      const int m = a >> 7;
      const int o = (a & 127) ^ ((m & 7) << 4);
      gload_lds16((const char*)wsrc + (size_t)m * K2 * 2 + s * 128 + o, dst + ub);
    }
  };
  // stage 128-node x 64-ch X slab (16KB); each wave covers 2KB
  auto stageX = [&](int s) {
    #pragma unroll
    for (int i = 0; i < 2; ++i) {
      const int ub = wave * 2048 + i * 1024;
      const int a = ub + lane * 16;
      const int m = a >> 7;
      const int o = (a & 127) ^ ((m & 7) << 4);
      int nd = n0 + m; if (nd >= n) nd = n - 1;
      gload_lds16((const char*)xin + (size_t)nd * 128 * 2 + s * 128 + o, ldsX + ub);
    }
  };
  // one K=64 slab of MFMAs: W rows wave*32+ct*16+lr, X rows rowOff+r*16+lr
  auto mfma_slab = [&](const char* wbuf, const char* xbase, int rowOff) {
    #pragma unroll
    for (int k0 = 0; k0 < 64; k0 += 32) {
      const int kb = (k0 + lg * 8) * 2;
      bf16x8 wfr[2];
      #pragma unroll
      for (int ct = 0; ct < 2; ++ct) {
        int m = wave * 32 + ct * 16 + lr;
        wfr[ct] = __builtin_bit_cast(bf16x8,
                  *(const uint4*)(wbuf + ((m * 128 + kb) ^ ((m & 7) << 4))));
      }
      #pragma unroll
      for (int r = 0; r < 8; ++r) {
        int xr = rowOff + r * 16 + lr;
        bf16x8 xf = __builtin_bit_cast(bf16x8,
                    *(const uint4*)(xbase + ((xr * 128 + kb) ^ ((xr & 7) << 4))));
        #pragma unroll
        for (int ct = 0; ct < 2; ++ct)
          acc[r][ct] = __builtin_amdgcn_mfma_f32_16x16x32_bf16(wfr[ct], xf, acc[r][ct], 0, 0, 0);
      }
    }
  };
  auto zacc = [&]() {
    #pragma unroll
    for (int r = 0; r < 8; ++r)
      #pragma unroll
      for (int c = 0; c < 2; ++c) acc[r][c] = (f32x4){0.f, 0.f, 0.f, 0.f};
  };
  // write this wave's 32ch x 128node tile into ldsH (K-slab layout)
  auto writeH = [&](const float* bias, bool act) {
    #pragma unroll
    for (int ct = 0; ct < 2; ++ct) {
      const int c0 = wave * 32 + ct * 16 + lg * 4;     // global channel 0..255
      const float4 bv = *(const float4*)(bias + c0);
      const int slab = c0 >> 6, cis = (c0 & 63) * 2;   // K-slab, byte col in slab
      #pragma unroll
      for (int r = 0; r < 8; ++r) {
        const int rowH = slab * 128 + r * 16 + lr;
        const f32x4 a = acc[r][ct];
        ushort4 o;
        if (act) {
          o.x = f2bf(actf<1>(a[0] + bv.x)); o.y = f2bf(actf<1>(a[1] + bv.y));
          o.z = f2bf(actf<1>(a[2] + bv.z)); o.w = f2bf(actf<1>(a[3] + bv.w));
        } else {
          o.x = f2bf(a[0] + bv.x); o.y = f2bf(a[1] + bv.y);
          o.z = f2bf(a[2] + bv.z); o.w = f2bf(a[3] + bv.w);
        }
        *(ushort4*)(ldsH + ((rowH * 128 + cis) ^ ((rowH & 7) << 4))) = o;
      }
    }
  };

  // ---- c1: h1 = X(128) @ Wc1^T + bc1 ----
  zacc();
  #pragma unroll
  for (int s = 0; s < 2; ++s) {
    if (s) __syncthreads();
    stageX(s);
    stageW(wc1, 128, s, ldsW0);
    asm volatile("s_waitcnt vmcnt(0)" ::: "memory");
    __syncthreads();
    mfma_slab(ldsW0, ldsX, 0);
  }
  __syncthreads();
  writeH(bc1, false);                               // h1 -> ldsH

  // ---- c2 (g=0): h2 = lrelu(h1 @ Wcl0^T + bcl0) -> ldsH
  // ---- c3 (g=1): logit = lrelu(h2 @ Wcl1^T + bcl1) . Wf + bf -> sigmoid
  for (int g = 0; g < 2; ++g) {
    const ushort* Wg = wcl + g * 65536;
    const float*  bg = bcl + g * 256;
    zacc();
    __syncthreads();                                // h-writes visible; ldsW free
    stageW(Wg, 256, 0, ldsW0);
    #pragma unroll
    for (int s = 0; s < 4; ++s) {
      char* cur = (s & 1) ? ldsW1 : ldsW0;
      char* nxt = (s & 1) ? ldsW0 : ldsW1;
      if (s + 1 < 4) {
        stageW(Wg, 256, s + 1, nxt);
        asm volatile("s_waitcnt vmcnt(4)" ::: "memory");
      } else {
        asm volatile("s_waitcnt vmcnt(0)" ::: "memory");
      }
      __syncthreads();
      mfma_slab(cur, ldsH, s * 128);
      __syncthreads();
    }
    if (g == 0) {
      writeH(bg, true);                             // h2 -> ldsH (in place)
    } else {
      float* red = (float*)ldsX;                    // 8 waves x 128 nodes
      #pragma unroll
      for (int r = 0; r < 8; ++r) {
        float p = 0.f;
        #pragma unroll
        for (int ct = 0; ct < 2; ++ct) {
          const int c0 = wave * 32 + ct * 16 + lg * 4;
          const float4 bv = *(const float4*)(bg + c0);
          const float4 wv = *(const float4*)(wfv + c0);
          const f32x4 a = acc[r][ct];
          p += actf<1>(a[0] + bv.x) * wv.x + actf<1>(a[1] + bv.y) * wv.y
             + actf<1>(a[2] + bv.z) * wv.z + actf<1>(a[3] + bv.w) * wv.w;
        }
        p += __shfl_xor(p, 16);
        p += __shfl_xor(p, 32);
        if (lg == 0) red[wave * 128 + r * 16 + lr] = p;
      }
      __syncthreads();
      if (tid < 128) {
        const int nd = n0 + tid;
        if (nd < n) {
          float logit = bfp[0];
          #pragma unroll
          for (int w = 0; w < 8; ++w) logit += red[w * 128 + tid];
          out[nd] = 1.f / (1.f + expf(-logit));
        }
      }
    }
  }
}

// ---------------- launch ----------------
extern "C" void kernel_launch(void* const* d_in, const int* in_sizes, int n_in,
                              void* d_out, int out_size, void* d_ws, size_t ws_size,
                              hipStream_t stream)
{
  const float* x    = (const float*)d_in[0];
  const int*   ei   = (const int*)d_in[1];
  const float* eps1 = (const float*)d_in[3];
  const float* W1   = (const float*)d_in[4];
  const float* b1   = (const float*)d_in[5];
  const float* g1   = (const float*)d_in[6];
  const float* be1  = (const float*)d_in[7];
  const float* m1   = (const float*)d_in[8];
  const float* v1   = (const float*)d_in[9];
  const float* epsL = (const float*)d_in[10];
  const float* WL   = (const float*)d_in[11];
  const float* bL   = (const float*)d_in[12];
  const float* gL   = (const float*)d_in[13];
  const float* beL  = (const float*)d_in[14];
  const float* mL   = (const float*)d_in[15];
  const float* vL   = (const float*)d_in[16];
  const float* Wc1  = (const float*)d_in[17];
  const float* bc1  = (const float*)d_in[18];
  const float* Wcl  = (const float*)d_in[19];
  const float* bcl  = (const float*)d_in[20];
  const float* Wf   = (const float*)d_in[21];
  const float* bfp  = (const float*)d_in[22];
  float* out = (float*)d_out;

  char* w = (char*)d_ws;
  size_t off = 0;
  auto alloc = [&](size_t bytes) {
    char* p = w + off;
    off += (bytes + 255) & ~(size_t)255;
    return p;
  };
  ushort* bufA   = (ushort*)alloc((size_t)NN * 256 * 2);   // 51.2 MB
  ushort* bufB   = (ushort*)alloc((size_t)NN * 256 * 2);   // 51.2 MB
  int*    rowp   = (int*)alloc((NN + 1) * 4);
  int*    deg    = (int*)alloc(NN * 4);
  int*    colb   = (int*)alloc((size_t)EE * 4);
  uint*   ebkt   = (uint*)alloc((size_t)EE * 4);
  int*    hist   = (int*)alloc((size_t)NCH * NBK * 4);     // 613 KB
  int*    bh     = (int*)alloc(NBK * 4);
  int*    boff   = (int*)alloc((NBK + 1) * 4);
  int*    partial= (int*)alloc(1024);
  ushort* wt1    = (ushort*)alloc(8192 * 2);
  ushort* wtL    = (ushort*)alloc(49152 * 2);
  ushort* wtc1   = (ushort*)alloc(32768 * 2);
  ushort* wtcl   = (ushort*)alloc(131072 * 2);
  float*  sc     = (float*)alloc(512 * 4);
  float*  tc     = (float*)alloc(512 * 4);
  (void)ws_size; (void)in_sizes; (void)n_in; (void)out_size;

  // multi-split CSR build (by dst), no global atomics in the scatter
  hipMemsetAsync(bh, 0, NBK * 4, stream);
  ms_hist_kernel<<<NCH, 256, 0, stream>>>(ei, hist, bh, EE);
  bkt_scan_kernel<<<1, 256, 0, stream>>>(bh, boff, EE);
  ms_offs_kernel<<<(NBK + 255) / 256, 256, 0, stream>>>(hist, boff);
  ms_scatter_kernel<<<NCH, 256, 0, stream>>>(ei, hist, ebkt, EE);
  bkt_deg_kernel<<<NBK, 256, 0, stream>>>(ebkt, boff, deg, NN);
  scan1_kernel<<<98, 256, 0, stream>>>(deg, rowp, partial, NN);
  scan2_kernel<<<1, 256, 0, stream>>>(partial, 98);
  scan3_kernel<<<(NN + 255) / 256, 256, 0, stream>>>(rowp, partial, NN, EE);
  bkt_fill_kernel<<<NBK, 256, 0, stream>>>(ebkt, boff, rowp, colb, NN);

  // prep
  bnprep_kernel<<<2, 256, 0, stream>>>(b1, g1, be1, m1, v1, bL, gL, beL, mL, vL, sc, tc);
  wtprep_kernel<<<864, 256, 0, stream>>>(W1, WL, Wc1, Wcl, wt1, wtL, wtc1, wtcl);
  xconv_kernel<<<(NN * CIN / 4 + 255) / 256, 256, 0, stream>>>(x, bufA, NN * CIN / 4);

  const int GB = (NN + 127) / 128;   // 782 node-tiles

  // GIN layer 1 (64 -> 128), double lrelu
  agg_kernel<64><<<25000, 256, 0, stream>>>(bufA, rowp, colb, eps1, bufB, NN);
  gemm_kernel<64, 128, 2, true><<<dim3(GB, 1), 256, 0, stream>>>(bufB, wt1, sc, tc, bufA, NN);
  // GIN layers 2-4 (128 -> 128), double lrelu
  for (int i = 0; i < 3; ++i) {
    agg_kernel<128><<<25000, 256, 0, stream>>>(bufA, rowp, colb, epsL + i, bufB, NN);
    gemm_kernel<128, 128, 2, true><<<dim3(GB, 1), 256, 0, stream>>>(
        bufB, wtL + i * 16384, sc + 128 * (i + 1), tc + 128 * (i + 1), bufA, NN);
  }
  // fused classifier + final (reads bufA, writes out)
  hipFuncSetAttribute(reinterpret_cast<const void*>(cls_kernel),
                      hipFuncAttributeMaxDynamicSharedMemorySize, 147456);
  cls_kernel<<<GB, 512, 147456, stream>>>(bufA, wtc1, bc1, wtcl, bcl, Wf, bfp, out, NN);
}